// Round 8
// baseline (631.212 us; speedup 1.0000x reference)
//
#include <hip/hip_runtime.h>
#include <math.h>

#define N_NODES 50000
#define N_EDGES 800000
#define NPAD 50176
#define HSTR 224   // hbuf row stride in HALFS: 448 B = exactly 4 x 128B sectors per row fetch
// ecsbuf (NPAD+2 ints): after k_sum8, ecsbuf[1+d] = total in-degree count;
// after scans, ecsbuf[1+d] = start(d). Readers: start(n)=ecsbuf[n+1], end=ecsbuf[n+2].
// In-degree histogram: 8-way split (blockIdx&7) returning atomics; rank[e] =
// (rank_within_copy << 3) | copy; k_sum8 folds copies -> totals + in-place
// exclusive per-bin prefix (cnt8 becomes prefix8).
// Out-degree histogram: ZERO global atomics — 196 LDS blocks (49 ranges x 1024
// bins x 4 edge-chunks) write deg_part[4][NPAD]; k_sum8 sums the 4 partials.
// (r7 lesson: atomic stream is throughput-bound at the coherence point, so the
// fix is fewer atomics, not more copies.)

typedef __attribute__((ext_vector_type(8))) short short8;
typedef __attribute__((ext_vector_type(4))) float f32x4;
typedef __attribute__((ext_vector_type(4))) _Float16 half4;

// ---------------- helpers ----------------

__device__ __forceinline__ float fast_tanh(float x) {
    float e = __expf(2.0f * x);
    float r = __builtin_amdgcn_rcpf(e + 1.0f);
    return 1.0f - 2.0f * r;
}

__device__ __forceinline__ unsigned short rne_bf16(float x) {
    unsigned u = __builtin_bit_cast(unsigned, x);
    return (unsigned short)((u + 0x7FFFu + ((u >> 16) & 1u)) >> 16);
}

__device__ __forceinline__ void split_bf16(float x, unsigned short& hi, unsigned short& lo) {
    hi = rne_bf16(x);
    float hf = __builtin_bit_cast(float, (unsigned)hi << 16);
    lo = rne_bf16(x - hf);
}

__device__ __forceinline__ f32x4 mfma16(short8 a, short8 b, f32x4 c) {
    return __builtin_amdgcn_mfma_f32_16x16x32_bf16(a, b, c, 0, 0, 0);
}

__device__ __forceinline__ void wsplit_one(const float* __restrict__ W, int KIN, int LDA,
                                           unsigned short* __restrict__ WT_hi,
                                           unsigned short* __restrict__ WT_lo, int idx) {
    int n = idx / LDA;
    int k = idx - n * LDA;
    float v = (n < 220 && k < KIN) ? W[k * 220 + n] : 0.f;
    unsigned short hi, lo;
    split_bf16(v, hi, lo);
    WT_hi[idx] = hi;
    WT_lo[idx] = lo;
}

// ---------------- CSR build ----------------

// partitioned launch:
// [0,782)     dst returning-atomic hist (8-way copies) + rank, 4 edges/thread
// [782,978)   out-degree LDS histogram: 49 ranges x 4 chunks, no global atomics
// [978,1398)  weight splits (28 + 196 + 196)
__global__ void k_build(const int* __restrict__ ei, int* __restrict__ deg_part,
                        int* __restrict__ cnt8, int* __restrict__ rank,
                        const float* __restrict__ W0, const float* __restrict__ W1,
                        const float* __restrict__ W2,
                        unsigned short* __restrict__ wt0h, unsigned short* __restrict__ wt0l,
                        unsigned short* __restrict__ wt1h, unsigned short* __restrict__ wt1l,
                        unsigned short* __restrict__ wt2h, unsigned short* __restrict__ wt2l) {
    int bx = blockIdx.x;
    if (bx < 782) {
        int c = bx & 7;                      // copy index ~ XCD id (round-robin)
        int* cntc = cnt8 + c * NPAD;
        int base = bx * 1024 + threadIdx.x;
#pragma unroll
        for (int i = 0; i < 4; ++i) {
            int e = base + i * 256;
            if (e < N_EDGES) {
                int r = atomicAdd(&cntc[ei[N_EDGES + e]], 1);
                rank[e] = (r << 3) | c;
            }
        }
    } else if (bx < 978) {
        __shared__ int hcnt[1024];
        int b2 = bx - 782;
        int rng = b2 >> 2, chk = b2 & 3;
        int lo = rng << 10;                  // 49 ranges x 1024 bins = 50176
        for (int i = threadIdx.x; i < 1024; i += 256) hcnt[i] = 0;
        __syncthreads();
        int ebeg = chk * 200000, eend = ebeg + 200000;
        for (int e = ebeg + threadIdx.x; e < eend; e += 256) {
            int sdx = ei[e] - lo;            // src value
            if ((unsigned)sdx < 1024u) atomicAdd(&hcnt[sdx], 1);
        }
        __syncthreads();
        for (int i = threadIdx.x; i < 1024; i += 256)
            deg_part[chk * NPAD + lo + i] = hcnt[i];
    } else if (bx < 1006) {
        int idx = (bx - 978) * 256 + threadIdx.x;           // 224*32 = 7168
        if (idx < 224 * 32) wsplit_one(W0, 22, 32, wt0h, wt0l, idx);
    } else if (bx < 1202) {
        int idx = (bx - 1006) * 256 + threadIdx.x;          // 224*224 = 50176
        wsplit_one(W1, 220, 224, wt1h, wt1l, idx);
    } else {
        int idx = (bx - 1202) * 256 + threadIdx.x;
        wsplit_one(W2, 220, 224, wt2h, wt2l, idx);
    }
}

// fold: cnt8 -> in-place exclusive per-bin prefix (prefix8), ecsbuf[1+d] = total;
// deg_out[d] = sum of 4 LDS-histogram partials. No pre-memset needed for outputs.
__global__ void k_sum8(int* __restrict__ cnt8, const int* __restrict__ deg_part,
                       int* __restrict__ ecsbuf, int* __restrict__ deg_out) {
    int d = blockIdx.x * 256 + threadIdx.x;
    if (d >= NPAD) return;
    int s = 0;
#pragma unroll
    for (int c = 0; c < 8; ++c) {
        int v = cnt8[c * NPAD + d];
        cnt8[c * NPAD + d] = s;
        s += v;
    }
    ecsbuf[1 + d] = s;
    if (d == 0) ecsbuf[0] = 0;
    deg_out[d] = deg_part[d] + deg_part[NPAD + d] + deg_part[2 * NPAD + d] + deg_part[3 * NPAD + d];
}

__global__ void k_scan1(const int* __restrict__ in, int* __restrict__ out,
                        int* __restrict__ bsum, int n) {
    __shared__ int s[256];
    int i = blockIdx.x * 256 + threadIdx.x;
    int v = (i < n) ? in[i] : 0;
    s[threadIdx.x] = v;
    __syncthreads();
    for (int off = 1; off < 256; off <<= 1) {
        int t = (threadIdx.x >= off) ? s[threadIdx.x - off] : 0;
        __syncthreads();
        s[threadIdx.x] += t;
        __syncthreads();
    }
    if (i < n) out[i] = s[threadIdx.x] - v;   // exclusive
    if (threadIdx.x == 255 && bsum) bsum[blockIdx.x] = s[255];
}

__global__ void k_scan_mid(int* __restrict__ a, int n) {
    __shared__ int s[256];
    __shared__ int carry;
    if (threadIdx.x == 0) carry = 0;
    for (int base = 0; base < n; base += 256) {
        int i = base + threadIdx.x;
        int v = (i < n) ? a[i] : 0;
        s[threadIdx.x] = v;
        __syncthreads();
        for (int off = 1; off < 256; off <<= 1) {
            int t = (threadIdx.x >= off) ? s[threadIdx.x - off] : 0;
            __syncthreads();
            s[threadIdx.x] += t;
            __syncthreads();
        }
        int c = carry;
        if (i < n) a[i] = s[threadIdx.x] - v + c;
        __syncthreads();
        if (threadIdx.x == 0) carry = c + s[255];
        __syncthreads();
    }
}

__global__ void k_scan3(int* __restrict__ out, const int* __restrict__ bscan, int n) {
    int i = blockIdx.x * 256 + threadIdx.x;
    if (i < n) out[i] += bscan[blockIdx.x];
}

// fused post-scan: [0,196) invsqrt | [196,3321) atomic-free fill | [3321,5470) prescale xs
__global__ void k_post_scan(const int* __restrict__ ei, const int* __restrict__ ecsbuf,
                            const int* __restrict__ rank, const int* __restrict__ prefix8,
                            const int* __restrict__ deg_out, const float* __restrict__ x,
                            float* __restrict__ inv_out, float* __restrict__ inv_in,
                            int* __restrict__ src_sorted, float* __restrict__ xs) {
    int bx = blockIdx.x;
    if (bx < 196) {
        int n = bx * 256 + threadIdx.x;
        if (n >= N_NODES) return;
        int di = ecsbuf[n + 2] - ecsbuf[n + 1];
        int a = deg_out[n]; if (a < 1) a = 1;
        if (di < 1) di = 1;
        inv_out[n] = 1.0f / sqrtf((float)a);
        inv_in[n]  = 1.0f / sqrtf((float)di);
    } else if (bx < 3321) {
        int e = (bx - 196) * 256 + threadIdx.x;
        if (e < N_EDGES) {
            int d = ei[N_EDGES + e];
            int rc = rank[e];
            int c = rc & 7, r = rc >> 3;
            src_sorted[ecsbuf[1 + d] + prefix8[c * NPAD + d] + r] = ei[e];
        }
    } else {
        int idx = (bx - 3321) * 256 + threadIdx.x;   // n*11 + f2
        if (idx >= N_NODES * 11) return;
        int n = idx / 11;
        int f2 = idx - n * 11;
        int a = deg_out[n]; if (a < 1) a = 1;
        float sc = 1.0f / sqrtf((float)a);
        float2 v = *(const float2*)&x[n * 22 + f2 * 2];
        v.x *= sc; v.y *= sc;
        *(float2*)&xs[n * 22 + f2 * 2] = v;
    }
}

// ---------------- aggregation ----------------

// layer 0: gather pre-scaled xs (width 22), *inv_in, split to bf16 A (K pad 32).
__global__ void k_agg22_split(const float* __restrict__ xs,
                              const int* __restrict__ ecsbuf, const int* __restrict__ srcs,
                              const float* __restrict__ inv_in,
                              unsigned short* __restrict__ A_hi, unsigned short* __restrict__ A_lo) {
    int idx = blockIdx.x * 256 + threadIdx.x;
    int n = idx >> 4, f2 = idx & 15;
    if (n >= N_NODES) return;
    float ax = 0.f, ay = 0.f;
    if (f2 <= 10) {
        const float2* xb = (const float2*)(xs) + f2;
        int e = ecsbuf[n + 1], end = ecsbuf[n + 2];
        for (; e + 3 < end; e += 4) {
            int s0 = srcs[e], s1 = srcs[e + 1], s2 = srcs[e + 2], s3 = srcs[e + 3];
            float2 v0 = xb[s0 * 11], v1 = xb[s1 * 11];
            float2 v2 = xb[s2 * 11], v3 = xb[s3 * 11];
            ax += (v0.x + v1.x) + (v2.x + v3.x);
            ay += (v0.y + v1.y) + (v2.y + v3.y);
        }
        for (; e < end; ++e) {
            float2 v0 = xb[srcs[e] * 11];
            ax += v0.x;
            ay += v0.y;
        }
        float si = inv_in[n];
        ax *= si; ay *= si;
    }
    ushort2 h2, l2;
    split_bf16(ax, h2.x, l2.x);
    split_bf16(ay, h2.y, l2.y);
    *(ushort2*)&A_hi[n * 32 + f2 * 2] = h2;
    *(ushort2*)&A_lo[n * 32 + f2 * 2] = l2;
}

// width-220 gather (h stored fp16, row = 224 halfs = 448 B = 4 sectors) + *inv_in
// -> split bf16 A.  One node per 64-lane group; lanes 0..54 own 4 features
// (8 B half4 loads); 8 loads in flight; fp32 accumulation.
__global__ __launch_bounds__(256) void k_agg220_split(const _Float16* __restrict__ h,
                                                      const int* __restrict__ ecsbuf,
                                                      const int* __restrict__ srcs,
                                                      const float* __restrict__ inv_in,
                                                      unsigned short* __restrict__ A_hi,
                                                      unsigned short* __restrict__ A_lo) {
    int lane = threadIdx.x & 63;
    int n = blockIdx.x * 4 + (threadIdx.x >> 6);
    if (n >= N_NODES || lane >= 56) return;   // no barriers; early-exit safe
    size_t ob = (size_t)n * 224 + lane * 4;
    if (lane == 55) {                          // K-pad columns 220..223 = 0
        ushort4 z = {0, 0, 0, 0};
        *(ushort4*)&A_hi[ob] = z;
        *(ushort4*)&A_lo[ob] = z;
        return;
    }
    int f4 = lane * 4;
    const _Float16* hb = h + f4;
    int e = ecsbuf[n + 1], end = ecsbuf[n + 2];
    float4 a0 = {0,0,0,0}, a1 = {0,0,0,0}, a2 = {0,0,0,0}, a3 = {0,0,0,0};
    for (; e + 7 < end; e += 8) {
        int s0 = srcs[e],     s1 = srcs[e + 1], s2 = srcs[e + 2], s3 = srcs[e + 3];
        int s4 = srcs[e + 4], s5 = srcs[e + 5], s6 = srcs[e + 6], s7 = srcs[e + 7];
        half4 v0 = *(const half4*)(hb + (size_t)s0 * HSTR);
        half4 v1 = *(const half4*)(hb + (size_t)s1 * HSTR);
        half4 v2 = *(const half4*)(hb + (size_t)s2 * HSTR);
        half4 v3 = *(const half4*)(hb + (size_t)s3 * HSTR);
        half4 v4 = *(const half4*)(hb + (size_t)s4 * HSTR);
        half4 v5 = *(const half4*)(hb + (size_t)s5 * HSTR);
        half4 v6 = *(const half4*)(hb + (size_t)s6 * HSTR);
        half4 v7 = *(const half4*)(hb + (size_t)s7 * HSTR);
        a0.x += (float)v0.x; a0.y += (float)v0.y; a0.z += (float)v0.z; a0.w += (float)v0.w;
        a1.x += (float)v1.x; a1.y += (float)v1.y; a1.z += (float)v1.z; a1.w += (float)v1.w;
        a2.x += (float)v2.x; a2.y += (float)v2.y; a2.z += (float)v2.z; a2.w += (float)v2.w;
        a3.x += (float)v3.x; a3.y += (float)v3.y; a3.z += (float)v3.z; a3.w += (float)v3.w;
        a0.x += (float)v4.x; a0.y += (float)v4.y; a0.z += (float)v4.z; a0.w += (float)v4.w;
        a1.x += (float)v5.x; a1.y += (float)v5.y; a1.z += (float)v5.z; a1.w += (float)v5.w;
        a2.x += (float)v6.x; a2.y += (float)v6.y; a2.z += (float)v6.z; a2.w += (float)v6.w;
        a3.x += (float)v7.x; a3.y += (float)v7.y; a3.z += (float)v7.z; a3.w += (float)v7.w;
    }
    for (; e + 3 < end; e += 4) {
        int s0 = srcs[e], s1 = srcs[e + 1], s2 = srcs[e + 2], s3 = srcs[e + 3];
        half4 v0 = *(const half4*)(hb + (size_t)s0 * HSTR);
        half4 v1 = *(const half4*)(hb + (size_t)s1 * HSTR);
        half4 v2 = *(const half4*)(hb + (size_t)s2 * HSTR);
        half4 v3 = *(const half4*)(hb + (size_t)s3 * HSTR);
        a0.x += (float)v0.x; a0.y += (float)v0.y; a0.z += (float)v0.z; a0.w += (float)v0.w;
        a1.x += (float)v1.x; a1.y += (float)v1.y; a1.z += (float)v1.z; a1.w += (float)v1.w;
        a2.x += (float)v2.x; a2.y += (float)v2.y; a2.z += (float)v2.z; a2.w += (float)v2.w;
        a3.x += (float)v3.x; a3.y += (float)v3.y; a3.z += (float)v3.z; a3.w += (float)v3.w;
    }
    for (; e < end; ++e) {
        half4 v = *(const half4*)(hb + (size_t)srcs[e] * HSTR);
        a0.x += (float)v.x; a0.y += (float)v.y; a0.z += (float)v.z; a0.w += (float)v.w;
    }
    float sc = inv_in[n];
    float4 t;
    t.x = ((a0.x + a1.x) + (a2.x + a3.x)) * sc;
    t.y = ((a0.y + a1.y) + (a2.y + a3.y)) * sc;
    t.z = ((a0.z + a1.z) + (a2.z + a3.z)) * sc;
    t.w = ((a0.w + a1.w) + (a2.w + a3.w)) * sc;
    ushort4 h4, l4;
    split_bf16(t.x, h4.x, l4.x);
    split_bf16(t.y, h4.y, l4.y);
    split_bf16(t.z, h4.z, l4.z);
    split_bf16(t.w, h4.w, l4.w);
    *(ushort4*)&A_hi[ob] = h4;
    *(ushort4*)&A_lo[ob] = l4;
}

// layer 3: gather tmp10 halves (width 10 x 2, 4 MB -> L2-resident), *inv_in + bias
__global__ void k_agg10_epi(const float* __restrict__ tmp, const int* __restrict__ ecsbuf,
                            const int* __restrict__ srcs, const float* __restrict__ inv_in,
                            const float* __restrict__ bias, float* __restrict__ out) {
    int idx = blockIdx.x * 256 + threadIdx.x;
    if (idx >= N_NODES * 5) return;
    int n = idx / 5;
    int f2 = idx - n * 5;
    const float2* tb0 = (const float2*)(tmp) + f2;
    const float2* tb1 = (const float2*)(tmp + (size_t)NPAD * 10) + f2;
    float ax = 0.f, ay = 0.f;
    int e = ecsbuf[n + 1], end = ecsbuf[n + 2];
    for (; e + 1 < end; e += 2) {
        float2 u0 = tb0[srcs[e] * 5],     w0 = tb1[srcs[e] * 5];
        float2 u1 = tb0[srcs[e + 1] * 5], w1 = tb1[srcs[e + 1] * 5];
        ax += (u0.x + w0.x) + (u1.x + w1.x);
        ay += (u0.y + w0.y) + (u1.y + w1.y);
    }
    if (e < end) {
        float2 u0 = tb0[srcs[e] * 5], w0 = tb1[srcs[e] * 5];
        ax += u0.x + w0.x;
        ay += u0.y + w0.y;
    }
    float si = inv_in[n];
    float2 o;
    o.x = ax * si + bias[f2 * 2];
    o.y = ay * si + bias[f2 * 2 + 1];
    *(float2*)&out[n * 10 + f2 * 2] = o;
}

// ---------------- MFMA split-bf16 GEMM (r4 shape + XCD-aligned rows) ---------
// D = A@W via A_hi*W_hi + A_hi*W_lo + A_lo*W_hi (~fp32 precision).
// Wave = 16 rows x 112 cols (acc[7] = 28 VGPR, VGPR ~84, no spill at (256,4)).
// Block = 4 waves = 64 rows x one col-half; grid 1568.
// XCD alignment (LDA==224 only): A rows for a block are exactly those written
// by agg220 blocks g == bid (mod 8) — row(i) = 4s + 512v + 32*(4w + i/4) + i%4
// with s=bid&7, ch=(bid>>3)&1, v=bid>>4. Under round-robin dispatch this makes
// A reads XCD-local L2 hits (r1 vs r5 FETCH delta showed cross-XCD A misses);
// the two col-half blocks (bid, bid+8) share A on the same XCD.
template <int KSTEPS, int LDA, bool FUSE_W3>
__global__ __launch_bounds__(256, 4) void k_gemm_mfma(const unsigned short* __restrict__ A_hi,
                                                      const unsigned short* __restrict__ A_lo,
                                                      const unsigned short* __restrict__ WT_hi,
                                                      const unsigned short* __restrict__ WT_lo,
                                                      const float* __restrict__ bias,
                                                      const float* __restrict__ post,
                                                      _Float16* __restrict__ out,
                                                      const float* __restrict__ W3,
                                                      float* __restrict__ tmp) {
    constexpr bool SWZ = (LDA == 224);
    int tid = threadIdx.x;
    int l = tid & 63, w = tid >> 6;
    int lrow = l & 15, q = l >> 4;
    int bid = blockIdx.x;

    int ch, s = 0, v = 0, rt = 0;
    if constexpr (SWZ) {
        s = bid & 7;
        int u = bid >> 3;
        ch = u & 1;
        v = u >> 1;                 // [0,98)
    } else {
        ch = bid & 1;
        rt = (bid >> 1) * 64 + w * 16;
    }
    int cb = ch * 112;

    // logical tile row i (0..15) -> physical A/out row
    auto prow = [&](int i) -> int {
        if constexpr (SWZ) return 4 * s + 512 * v + 32 * (4 * w + (i >> 2)) + (i & 3);
        else return rt + i;
    };

    int arow = prow(lrow);
    const unsigned short* pah = A_hi + (size_t)arow * LDA + q * 8;
    const unsigned short* pal = A_lo + (size_t)arow * LDA + q * 8;
    const unsigned short* pbh = WT_hi + (size_t)(cb + lrow) * LDA + q * 8;
    const unsigned short* pbl = WT_lo + (size_t)(cb + lrow) * LDA + q * 8;

    f32x4 acc[7];
#pragma unroll
    for (int ct = 0; ct < 7; ++ct) acc[ct] = (f32x4){0.f, 0.f, 0.f, 0.f};

#pragma unroll
    for (int ks = 0; ks < KSTEPS; ++ks) {
        int k0 = ks * 32;
        short8 ah = *(const short8*)(const void*)(pah + k0);
        short8 al = *(const short8*)(const void*)(pal + k0);
#pragma unroll
        for (int ct = 0; ct < 7; ++ct) {
            size_t boff = (size_t)(ct * 16) * LDA + k0;
            short8 bh = *(const short8*)(const void*)(pbh + boff);
            short8 bl = *(const short8*)(const void*)(pbl + boff);
            acc[ct] = mfma16(ah, bh, acc[ct]);
            acc[ct] = mfma16(ah, bl, acc[ct]);
            acc[ct] = mfma16(al, bh, acc[ct]);
        }
    }

    float pv[4];
#pragma unroll
    for (int r = 0; r < 4; ++r) {
        int r0 = prow(q * 4 + r);
        pv[r] = (r0 < N_NODES) ? post[r0] : 0.f;
    }

    if (!FUSE_W3) {
#pragma unroll
        for (int ct = 0; ct < 7; ++ct) {
            int col = cb + ct * 16 + lrow;
            if (col >= 220) continue;
            float bv = bias[col];
#pragma unroll
            for (int r = 0; r < 4; ++r) {
                int r0 = prow(q * 4 + r);
                if (r0 < N_NODES)
                    out[(size_t)r0 * HSTR + col] = (_Float16)(pv[r] * fast_tanh(acc[ct][r] + bv));
            }
        }
    } else {
        float p[4][10];
#pragma unroll
        for (int r = 0; r < 4; ++r)
#pragma unroll
            for (int j = 0; j < 10; ++j) p[r][j] = 0.f;
#pragma unroll
        for (int ct = 0; ct < 7; ++ct) {
            int col = cb + ct * 16 + lrow;
            bool cok = col < 220;
            float bv = cok ? bias[col] : 0.f;
            float w3v[10];
            if (cok) {
                const float2* wp = (const float2*)&W3[col * 10];
#pragma unroll
                for (int j2 = 0; j2 < 5; ++j2) {
                    float2 t = wp[j2];
                    w3v[2 * j2] = t.x;
                    w3v[2 * j2 + 1] = t.y;
                }
            } else {
#pragma unroll
                for (int j = 0; j < 10; ++j) w3v[j] = 0.f;
            }
#pragma unroll
            for (int r = 0; r < 4; ++r) {
                float h2 = pv[r] * fast_tanh(acc[ct][r] + bv);
#pragma unroll
                for (int j = 0; j < 10; ++j) p[r][j] += h2 * w3v[j];
            }
        }
        // reduce over the 16 lanes (same q) sharing each row
#pragma unroll
        for (int r = 0; r < 4; ++r)
#pragma unroll
            for (int j = 0; j < 10; ++j) {
                float vv = p[r][j];
                vv += __shfl_xor(vv, 1, 64);
                vv += __shfl_xor(vv, 2, 64);
                vv += __shfl_xor(vv, 4, 64);
                vv += __shfl_xor(vv, 8, 64);
                p[r][j] = vv;
            }
        if (lrow == 0) {
#pragma unroll
            for (int r = 0; r < 4; ++r) {
                int row = prow(q * 4 + r);
                if (row < N_NODES) {
                    float* tp = tmp + ((size_t)ch * NPAD + row) * 10;
#pragma unroll
                    for (int j2 = 0; j2 < 5; ++j2) {
                        float2 o = {p[r][2 * j2], p[r][2 * j2 + 1]};
                        *(float2*)&tp[2 * j2] = o;
                    }
                }
            }
        }
    }
}

// ---------------- launch ----------------

extern "C" void kernel_launch(void* const* d_in, const int* in_sizes, int n_in,
                              void* d_out, int out_size, void* d_ws, size_t ws_size,
                              hipStream_t stream) {
    const float* x  = (const float*)d_in[0];
    const float* W0 = (const float*)d_in[1];
    const float* b0 = (const float*)d_in[2];
    const float* W1 = (const float*)d_in[3];
    const float* b1 = (const float*)d_in[4];
    const float* W2 = (const float*)d_in[5];
    const float* b2 = (const float*)d_in[6];
    const float* W3 = (const float*)d_in[7];
    const float* b3 = (const float*)d_in[8];
    const int*   ei = (const int*)d_in[9];
    float* out = (float*)d_out;

    int* ws = (int*)d_ws;
    // word offsets (wt1/wt2 = 224*224 ushorts = 25088 WORDS each)
    int* ecsbuf     = ws + 0;               // 50432 (50178 used; [0]=0)
    int* deg_out    = ws + 50432;           // 50176
    int* bsumA      = ws + 100608;          // 256 (196 used)
    float* inv_out  = (float*)(ws + 100864);
    float* inv_in   = (float*)(ws + 151040);
    int* src_sorted = ws + 201216;          // 800000
    unsigned short* wt0h = (unsigned short*)(ws + 1001216);   // 3584 w
    unsigned short* wt0l = (unsigned short*)(ws + 1004800);   // 3584 w
    unsigned short* wt1h = (unsigned short*)(ws + 1008384);   // 25088 w
    unsigned short* wt1l = (unsigned short*)(ws + 1033472);   // 25088 w
    unsigned short* wt2h = (unsigned short*)(ws + 1058560);   // 25088 w
    unsigned short* wt2l = (unsigned short*)(ws + 1083648);   // 25088 w
    unsigned short* ahi  = (unsigned short*)(ws + 1108736);   // 5619712 w
    unsigned short* alo  = (unsigned short*)(ws + 6728448);   // 5619712 w
    _Float16* hbuf = (_Float16*)(ws + 12348160); // 50000*224 halfs = 2800000 w
    float* tmp10 = (float*)(ws + 17948160); // 2*NPAD*10 = 1003520 w -> end 18951680
    // aliases in regions not yet live at CSR-build time:
    int* rank     = (int*)ahi;                        // ahi words [0, 800000)
    int* cnt8     = (int*)alo;                        // alo words [0, 401408)
    int* deg_part = (int*)alo + 8 * NPAD;             // alo words [401408, 602112)
    float* xs = (float*)(ws + 1108736 + 3000000);     // clear of rank & A22 region

    // zero only the 8 in-degree atomic copies (1.6 MB); deg_part fully written
    hipMemsetAsync(cnt8, 0, (size_t)8 * NPAD * sizeof(int), stream);

    // CSR build: dst-rank atomics + LDS out-degree hist + weight splits
    k_build<<<1398, 256, 0, stream>>>(ei, deg_part, cnt8, rank,
                                      W0, W1, W2, wt0h, wt0l, wt1h, wt1l, wt2h, wt2l);
    k_sum8<<<196, 256, 0, stream>>>(cnt8, deg_part, ecsbuf, deg_out);
    k_scan1<<<196, 256, 0, stream>>>(ecsbuf + 1, ecsbuf + 1, bsumA, NPAD);
    k_scan_mid<<<1, 256, 0, stream>>>(bsumA, 196);
    k_scan3<<<196, 256, 0, stream>>>(ecsbuf + 1, bsumA, NPAD);
    k_post_scan<<<5470, 256, 0, stream>>>(ei, ecsbuf, rank, cnt8, deg_out, x,
                                          inv_out, inv_in, src_sorted, xs);

    int gemm_grid = (NPAD / 64) * 2;         // 1568 (both mappings)
    int agg_grid  = (N_NODES + 3) / 4;       // 12500

    // ---- layer 0
    k_agg22_split<<<(N_NODES * 16 + 255) / 256, 256, 0, stream>>>(
        xs, ecsbuf, src_sorted, inv_in, ahi, alo);
    k_gemm_mfma<1, 32, false><<<gemm_grid, 256, 0, stream>>>(
        ahi, alo, wt0h, wt0l, b0, inv_out, hbuf, nullptr, nullptr);

    // ---- layer 1
    k_agg220_split<<<agg_grid, 256, 0, stream>>>(hbuf, ecsbuf, src_sorted, inv_in, ahi, alo);
    k_gemm_mfma<7, 224, false><<<gemm_grid, 256, 0, stream>>>(
        ahi, alo, wt1h, wt1l, b1, inv_out, hbuf, nullptr, nullptr);

    // ---- layer 2 (+ fused W3 projection; h2 never materialized)
    k_agg220_split<<<agg_grid, 256, 0, stream>>>(hbuf, ecsbuf, src_sorted, inv_in, ahi, alo);
    k_gemm_mfma<7, 224, true><<<gemm_grid, 256, 0, stream>>>(
        ahi, alo, wt2h, wt2l, b2, inv_out, nullptr, W3, tmp10);

    // ---- layer 3
    k_agg10_epi<<<(N_NODES * 5 + 255) / 256, 256, 0, stream>>>(
        tmp10, ecsbuf, src_sorted, inv_in, b3, out);
}

// Round 10
// 464.232 us; speedup vs baseline: 1.3597x; 1.3597x over previous
//
#include <hip/hip_runtime.h>
#include <math.h>

#define N_NODES 50000
#define N_EDGES 800000
#define NPAD 50176
#define HSTR 224   // hbuf row stride in HALFS: 448 B = exactly 4 x 128B sectors per row fetch
// ecsbuf (NPAD+2 ints): after k_sum8, ecsbuf[1+d] = total in-degree count;
// after scans, ecsbuf[1+d] = start(d). Readers: start(n)=ecsbuf[n+1], end=ecsbuf[n+2].
// Histograms are 8-way split by blockIdx&7 (XCD round-robin): cnt8/deg8 copies,
// rank[e] = (rank_within_copy << 3) | copy. k_sum8 folds copies -> totals +
// in-place exclusive per-bin prefix over copies (cnt8 becomes prefix8).
// (r7: 8-way split = null vs 1-way -> atomic stream is throughput-bound at the
// coherence point ~22G/s; r8: LDS-hist alternative was 49x read-amplified and
// far worse. 73us atomic hist is the established floor for this build.)

typedef __attribute__((ext_vector_type(8))) short short8;
typedef __attribute__((ext_vector_type(4))) float f32x4;
typedef __attribute__((ext_vector_type(4))) _Float16 half4;

// ---------------- helpers ----------------

__device__ __forceinline__ float fast_tanh(float x) {
    float e = __expf(2.0f * x);
    float r = __builtin_amdgcn_rcpf(e + 1.0f);
    return 1.0f - 2.0f * r;
}

__device__ __forceinline__ unsigned short rne_bf16(float x) {
    unsigned u = __builtin_bit_cast(unsigned, x);
    return (unsigned short)((u + 0x7FFFu + ((u >> 16) & 1u)) >> 16);
}

__device__ __forceinline__ void split_bf16(float x, unsigned short& hi, unsigned short& lo) {
    hi = rne_bf16(x);
    float hf = __builtin_bit_cast(float, (unsigned)hi << 16);
    lo = rne_bf16(x - hf);
}

__device__ __forceinline__ f32x4 mfma16(short8 a, short8 b, f32x4 c) {
    return __builtin_amdgcn_mfma_f32_16x16x32_bf16(a, b, c, 0, 0, 0);
}

__device__ __forceinline__ void wsplit_one(const float* __restrict__ W, int KIN, int LDA,
                                           unsigned short* __restrict__ WT_hi,
                                           unsigned short* __restrict__ WT_lo, int idx) {
    int n = idx / LDA;
    int k = idx - n * LDA;
    float v = (n < 220 && k < KIN) ? W[k * 220 + n] : 0.f;
    unsigned short hi, lo;
    split_bf16(v, hi, lo);
    WT_hi[idx] = hi;
    WT_lo[idx] = lo;
}

// ---------------- CSR build ----------------

// partitioned launch: [0,782) 8-way-split histograms + per-edge rank, 4 edges/
// thread (4 independent returning atomics in flight); [782,1202) weight splits.
__global__ void k_hist_wsplit(const int* __restrict__ ei, int* __restrict__ deg8,
                              int* __restrict__ cnt8, int* __restrict__ rank,
                              const float* __restrict__ W0, const float* __restrict__ W1,
                              const float* __restrict__ W2,
                              unsigned short* __restrict__ wt0h, unsigned short* __restrict__ wt0l,
                              unsigned short* __restrict__ wt1h, unsigned short* __restrict__ wt1l,
                              unsigned short* __restrict__ wt2h, unsigned short* __restrict__ wt2l) {
    int bx = blockIdx.x;
    if (bx < 782) {
        int c = bx & 7;                      // copy index ~ XCD id (round-robin)
        int* degc = deg8 + c * NPAD;
        int* cntc = cnt8 + c * NPAD;
        int base = bx * 1024 + threadIdx.x;
#pragma unroll
        for (int i = 0; i < 4; ++i) {
            int e = base + i * 256;
            if (e < N_EDGES) {
                atomicAdd(&degc[ei[e]], 1);
                int r = atomicAdd(&cntc[ei[N_EDGES + e]], 1);
                rank[e] = (r << 3) | c;
            }
        }
    } else if (bx < 810) {
        int idx = (bx - 782) * 256 + threadIdx.x;           // 224*32 = 7168
        if (idx < 224 * 32) wsplit_one(W0, 22, 32, wt0h, wt0l, idx);
    } else if (bx < 1006) {
        int idx = (bx - 810) * 256 + threadIdx.x;           // 224*224 = 50176
        wsplit_one(W1, 220, 224, wt1h, wt1l, idx);
    } else {
        int idx = (bx - 1006) * 256 + threadIdx.x;
        wsplit_one(W2, 220, 224, wt2h, wt2l, idx);
    }
}

// fold 8 histogram copies: cnt8 -> in-place exclusive per-bin prefix (prefix8),
// ecsbuf[1+d] = total count, deg_out[d] = total out-degree. Covers all NPAD bins.
__global__ void k_sum8(int* __restrict__ cnt8, const int* __restrict__ deg8,
                       int* __restrict__ ecsbuf, int* __restrict__ deg_out) {
    int d = blockIdx.x * 256 + threadIdx.x;
    if (d >= NPAD) return;
    int s = 0;
#pragma unroll
    for (int c = 0; c < 8; ++c) {
        int v = cnt8[c * NPAD + d];
        cnt8[c * NPAD + d] = s;
        s += v;
    }
    ecsbuf[1 + d] = s;
    if (d == 0) ecsbuf[0] = 0;
    int t = 0;
#pragma unroll
    for (int c = 0; c < 8; ++c) t += deg8[c * NPAD + d];
    deg_out[d] = t;
}

__global__ void k_scan1(const int* __restrict__ in, int* __restrict__ out,
                        int* __restrict__ bsum, int n) {
    __shared__ int s[256];
    int i = blockIdx.x * 256 + threadIdx.x;
    int v = (i < n) ? in[i] : 0;
    s[threadIdx.x] = v;
    __syncthreads();
    for (int off = 1; off < 256; off <<= 1) {
        int t = (threadIdx.x >= off) ? s[threadIdx.x - off] : 0;
        __syncthreads();
        s[threadIdx.x] += t;
        __syncthreads();
    }
    if (i < n) out[i] = s[threadIdx.x] - v;   // exclusive
    if (threadIdx.x == 255 && bsum) bsum[blockIdx.x] = s[255];
}

__global__ void k_scan_mid(int* __restrict__ a, int n) {
    __shared__ int s[256];
    __shared__ int carry;
    if (threadIdx.x == 0) carry = 0;
    for (int base = 0; base < n; base += 256) {
        int i = base + threadIdx.x;
        int v = (i < n) ? a[i] : 0;
        s[threadIdx.x] = v;
        __syncthreads();
        for (int off = 1; off < 256; off <<= 1) {
            int t = (threadIdx.x >= off) ? s[threadIdx.x - off] : 0;
            __syncthreads();
            s[threadIdx.x] += t;
            __syncthreads();
        }
        int c = carry;
        if (i < n) a[i] = s[threadIdx.x] - v + c;
        __syncthreads();
        if (threadIdx.x == 0) carry = c + s[255];
        __syncthreads();
    }
}

__global__ void k_scan3(int* __restrict__ out, const int* __restrict__ bscan, int n) {
    int i = blockIdx.x * 256 + threadIdx.x;
    if (i < n) out[i] += bscan[blockIdx.x];
}

// fused post-scan: [0,196) invsqrt | [196,3321) atomic-free fill | [3321,5470) prescale xs
__global__ void k_post_scan(const int* __restrict__ ei, const int* __restrict__ ecsbuf,
                            const int* __restrict__ rank, const int* __restrict__ prefix8,
                            const int* __restrict__ deg_out, const float* __restrict__ x,
                            float* __restrict__ inv_out, float* __restrict__ inv_in,
                            int* __restrict__ src_sorted, float* __restrict__ xs) {
    int bx = blockIdx.x;
    if (bx < 196) {
        int n = bx * 256 + threadIdx.x;
        if (n >= N_NODES) return;
        int di = ecsbuf[n + 2] - ecsbuf[n + 1];
        int a = deg_out[n]; if (a < 1) a = 1;
        if (di < 1) di = 1;
        inv_out[n] = 1.0f / sqrtf((float)a);
        inv_in[n]  = 1.0f / sqrtf((float)di);
    } else if (bx < 3321) {
        int e = (bx - 196) * 256 + threadIdx.x;
        if (e < N_EDGES) {
            int d = ei[N_EDGES + e];
            int rc = rank[e];
            int c = rc & 7, r = rc >> 3;
            src_sorted[ecsbuf[1 + d] + prefix8[c * NPAD + d] + r] = ei[e];
        }
    } else {
        int idx = (bx - 3321) * 256 + threadIdx.x;   // n*11 + f2
        if (idx >= N_NODES * 11) return;
        int n = idx / 11;
        int f2 = idx - n * 11;
        int a = deg_out[n]; if (a < 1) a = 1;
        float sc = 1.0f / sqrtf((float)a);
        float2 v = *(const float2*)&x[n * 22 + f2 * 2];
        v.x *= sc; v.y *= sc;
        *(float2*)&xs[n * 22 + f2 * 2] = v;
    }
}

// ---------------- aggregation ----------------

// layer 0: gather pre-scaled xs (width 22), *inv_in, split to bf16 A (K pad 32).
__global__ void k_agg22_split(const float* __restrict__ xs,
                              const int* __restrict__ ecsbuf, const int* __restrict__ srcs,
                              const float* __restrict__ inv_in,
                              unsigned short* __restrict__ A_hi, unsigned short* __restrict__ A_lo) {
    int idx = blockIdx.x * 256 + threadIdx.x;
    int n = idx >> 4, f2 = idx & 15;
    if (n >= N_NODES) return;
    float ax = 0.f, ay = 0.f;
    if (f2 <= 10) {
        const float2* xb = (const float2*)(xs) + f2;
        int e = ecsbuf[n + 1], end = ecsbuf[n + 2];
        for (; e + 3 < end; e += 4) {
            int s0 = srcs[e], s1 = srcs[e + 1], s2 = srcs[e + 2], s3 = srcs[e + 3];
            float2 v0 = xb[s0 * 11], v1 = xb[s1 * 11];
            float2 v2 = xb[s2 * 11], v3 = xb[s3 * 11];
            ax += (v0.x + v1.x) + (v2.x + v3.x);
            ay += (v0.y + v1.y) + (v2.y + v3.y);
        }
        for (; e < end; ++e) {
            float2 v0 = xb[srcs[e] * 11];
            ax += v0.x;
            ay += v0.y;
        }
        float si = inv_in[n];
        ax *= si; ay *= si;
    }
    ushort2 h2, l2;
    split_bf16(ax, h2.x, l2.x);
    split_bf16(ay, h2.y, l2.y);
    *(ushort2*)&A_hi[n * 32 + f2 * 2] = h2;
    *(ushort2*)&A_lo[n * 32 + f2 * 2] = l2;
}

// width-220 gather (h stored fp16, row = 224 halfs = 448 B = 4 sectors) + *inv_in
// -> split bf16 A.  One node per 64-lane group; lanes 0..54 own 4 features
// (8 B half4 loads); 8 loads in flight; fp32 accumulation.
__global__ __launch_bounds__(256) void k_agg220_split(const _Float16* __restrict__ h,
                                                      const int* __restrict__ ecsbuf,
                                                      const int* __restrict__ srcs,
                                                      const float* __restrict__ inv_in,
                                                      unsigned short* __restrict__ A_hi,
                                                      unsigned short* __restrict__ A_lo) {
    int lane = threadIdx.x & 63;
    int n = blockIdx.x * 4 + (threadIdx.x >> 6);
    if (n >= N_NODES || lane >= 56) return;   // no barriers; early-exit safe
    size_t ob = (size_t)n * 224 + lane * 4;
    if (lane == 55) {                          // K-pad columns 220..223 = 0
        ushort4 z = {0, 0, 0, 0};
        *(ushort4*)&A_hi[ob] = z;
        *(ushort4*)&A_lo[ob] = z;
        return;
    }
    int f4 = lane * 4;
    const _Float16* hb = h + f4;
    int e = ecsbuf[n + 1], end = ecsbuf[n + 2];
    float4 a0 = {0,0,0,0}, a1 = {0,0,0,0}, a2 = {0,0,0,0}, a3 = {0,0,0,0};
    for (; e + 7 < end; e += 8) {
        int s0 = srcs[e],     s1 = srcs[e + 1], s2 = srcs[e + 2], s3 = srcs[e + 3];
        int s4 = srcs[e + 4], s5 = srcs[e + 5], s6 = srcs[e + 6], s7 = srcs[e + 7];
        half4 v0 = *(const half4*)(hb + (size_t)s0 * HSTR);
        half4 v1 = *(const half4*)(hb + (size_t)s1 * HSTR);
        half4 v2 = *(const half4*)(hb + (size_t)s2 * HSTR);
        half4 v3 = *(const half4*)(hb + (size_t)s3 * HSTR);
        half4 v4 = *(const half4*)(hb + (size_t)s4 * HSTR);
        half4 v5 = *(const half4*)(hb + (size_t)s5 * HSTR);
        half4 v6 = *(const half4*)(hb + (size_t)s6 * HSTR);
        half4 v7 = *(const half4*)(hb + (size_t)s7 * HSTR);
        a0.x += (float)v0.x; a0.y += (float)v0.y; a0.z += (float)v0.z; a0.w += (float)v0.w;
        a1.x += (float)v1.x; a1.y += (float)v1.y; a1.z += (float)v1.z; a1.w += (float)v1.w;
        a2.x += (float)v2.x; a2.y += (float)v2.y; a2.z += (float)v2.z; a2.w += (float)v2.w;
        a3.x += (float)v3.x; a3.y += (float)v3.y; a3.z += (float)v3.z; a3.w += (float)v3.w;
        a0.x += (float)v4.x; a0.y += (float)v4.y; a0.z += (float)v4.z; a0.w += (float)v4.w;
        a1.x += (float)v5.x; a1.y += (float)v5.y; a1.z += (float)v5.z; a1.w += (float)v5.w;
        a2.x += (float)v6.x; a2.y += (float)v6.y; a2.z += (float)v6.z; a2.w += (float)v6.w;
        a3.x += (float)v7.x; a3.y += (float)v7.y; a3.z += (float)v7.z; a3.w += (float)v7.w;
    }
    for (; e + 3 < end; e += 4) {
        int s0 = srcs[e], s1 = srcs[e + 1], s2 = srcs[e + 2], s3 = srcs[e + 3];
        half4 v0 = *(const half4*)(hb + (size_t)s0 * HSTR);
        half4 v1 = *(const half4*)(hb + (size_t)s1 * HSTR);
        half4 v2 = *(const half4*)(hb + (size_t)s2 * HSTR);
        half4 v3 = *(const half4*)(hb + (size_t)s3 * HSTR);
        a0.x += (float)v0.x; a0.y += (float)v0.y; a0.z += (float)v0.z; a0.w += (float)v0.w;
        a1.x += (float)v1.x; a1.y += (float)v1.y; a1.z += (float)v1.z; a1.w += (float)v1.w;
        a2.x += (float)v2.x; a2.y += (float)v2.y; a2.z += (float)v2.z; a2.w += (float)v2.w;
        a3.x += (float)v3.x; a3.y += (float)v3.y; a3.z += (float)v3.z; a3.w += (float)v3.w;
    }
    for (; e < end; ++e) {
        half4 v = *(const half4*)(hb + (size_t)srcs[e] * HSTR);
        a0.x += (float)v.x; a0.y += (float)v.y; a0.z += (float)v.z; a0.w += (float)v.w;
    }
    float sc = inv_in[n];
    float4 t;
    t.x = ((a0.x + a1.x) + (a2.x + a3.x)) * sc;
    t.y = ((a0.y + a1.y) + (a2.y + a3.y)) * sc;
    t.z = ((a0.z + a1.z) + (a2.z + a3.z)) * sc;
    t.w = ((a0.w + a1.w) + (a2.w + a3.w)) * sc;
    ushort4 h4, l4;
    split_bf16(t.x, h4.x, l4.x);
    split_bf16(t.y, h4.y, l4.y);
    split_bf16(t.z, h4.z, l4.z);
    split_bf16(t.w, h4.w, l4.w);
    *(ushort4*)&A_hi[ob] = h4;
    *(ushort4*)&A_lo[ob] = l4;
}

// layer 3: gather tmp10 halves (width 10 x 2, 4 MB -> L2-resident), *inv_in + bias
__global__ void k_agg10_epi(const float* __restrict__ tmp, const int* __restrict__ ecsbuf,
                            const int* __restrict__ srcs, const float* __restrict__ inv_in,
                            const float* __restrict__ bias, float* __restrict__ out) {
    int idx = blockIdx.x * 256 + threadIdx.x;
    if (idx >= N_NODES * 5) return;
    int n = idx / 5;
    int f2 = idx - n * 5;
    const float2* tb0 = (const float2*)(tmp) + f2;
    const float2* tb1 = (const float2*)(tmp + (size_t)NPAD * 10) + f2;
    float ax = 0.f, ay = 0.f;
    int e = ecsbuf[n + 1], end = ecsbuf[n + 2];
    for (; e + 1 < end; e += 2) {
        float2 u0 = tb0[srcs[e] * 5],     w0 = tb1[srcs[e] * 5];
        float2 u1 = tb0[srcs[e + 1] * 5], w1 = tb1[srcs[e + 1] * 5];
        ax += (u0.x + w0.x) + (u1.x + w1.x);
        ay += (u0.y + w0.y) + (u1.y + w1.y);
    }
    if (e < end) {
        float2 u0 = tb0[srcs[e] * 5], w0 = tb1[srcs[e] * 5];
        ax += u0.x + w0.x;
        ay += u0.y + w0.y;
    }
    float si = inv_in[n];
    float2 o;
    o.x = ax * si + bias[f2 * 2];
    o.y = ay * si + bias[f2 * 2 + 1];
    *(float2*)&out[n * 10 + f2 * 2] = o;
}

// ---------------- MFMA split-bf16 GEMM (r4 shape + XCD-aligned rows) ---------
// D = A@W via A_hi*W_hi + A_hi*W_lo + A_lo*W_hi (~fp32 precision).
// Wave = 16 rows x 112 cols (acc[7] = 28 VGPR, VGPR ~84, no spill at (256,4)).
// Block = 4 waves = 64 rows x one col-half; grid 1568.
// XCD alignment (LDA==224 only): A rows for a block are exactly those written
// by agg220 blocks g == bid (mod 8) — row(i) = 4s + 512v + 32*(4w + i/4) + i%4
// with s=bid&7, ch=(bid>>3)&1, v=bid>>4. Under round-robin dispatch this makes
// A reads XCD-local L2 hits; col-half blocks (bid, bid+8) share A on one XCD.
// (r8: this mapping verified passing; inferred ~50us total GEMM gain.)
template <int KSTEPS, int LDA, bool FUSE_W3>
__global__ __launch_bounds__(256, 4) void k_gemm_mfma(const unsigned short* __restrict__ A_hi,
                                                      const unsigned short* __restrict__ A_lo,
                                                      const unsigned short* __restrict__ WT_hi,
                                                      const unsigned short* __restrict__ WT_lo,
                                                      const float* __restrict__ bias,
                                                      const float* __restrict__ post,
                                                      _Float16* __restrict__ out,
                                                      const float* __restrict__ W3,
                                                      float* __restrict__ tmp) {
    constexpr bool SWZ = (LDA == 224);
    int tid = threadIdx.x;
    int l = tid & 63, w = tid >> 6;
    int lrow = l & 15, q = l >> 4;
    int bid = blockIdx.x;

    int ch, s = 0, v = 0, rt = 0;
    if constexpr (SWZ) {
        s = bid & 7;
        int u = bid >> 3;
        ch = u & 1;
        v = u >> 1;                 // [0,98)
    } else {
        ch = bid & 1;
        rt = (bid >> 1) * 64 + w * 16;
    }
    int cb = ch * 112;

    // logical tile row i (0..15) -> physical A/out row
    auto prow = [&](int i) -> int {
        if constexpr (SWZ) return 4 * s + 512 * v + 32 * (4 * w + (i >> 2)) + (i & 3);
        else return rt + i;
    };

    int arow = prow(lrow);
    const unsigned short* pah = A_hi + (size_t)arow * LDA + q * 8;
    const unsigned short* pal = A_lo + (size_t)arow * LDA + q * 8;
    const unsigned short* pbh = WT_hi + (size_t)(cb + lrow) * LDA + q * 8;
    const unsigned short* pbl = WT_lo + (size_t)(cb + lrow) * LDA + q * 8;

    f32x4 acc[7];
#pragma unroll
    for (int ct = 0; ct < 7; ++ct) acc[ct] = (f32x4){0.f, 0.f, 0.f, 0.f};

#pragma unroll
    for (int ks = 0; ks < KSTEPS; ++ks) {
        int k0 = ks * 32;
        short8 ah = *(const short8*)(const void*)(pah + k0);
        short8 al = *(const short8*)(const void*)(pal + k0);
#pragma unroll
        for (int ct = 0; ct < 7; ++ct) {
            size_t boff = (size_t)(ct * 16) * LDA + k0;
            short8 bh = *(const short8*)(const void*)(pbh + boff);
            short8 bl = *(const short8*)(const void*)(pbl + boff);
            acc[ct] = mfma16(ah, bh, acc[ct]);
            acc[ct] = mfma16(ah, bl, acc[ct]);
            acc[ct] = mfma16(al, bh, acc[ct]);
        }
    }

    float pv[4];
#pragma unroll
    for (int r = 0; r < 4; ++r) {
        int r0 = prow(q * 4 + r);
        pv[r] = (r0 < N_NODES) ? post[r0] : 0.f;
    }

    if (!FUSE_W3) {
#pragma unroll
        for (int ct = 0; ct < 7; ++ct) {
            int col = cb + ct * 16 + lrow;
            if (col >= 220) continue;
            float bv = bias[col];
#pragma unroll
            for (int r = 0; r < 4; ++r) {
                int r0 = prow(q * 4 + r);
                if (r0 < N_NODES)
                    out[(size_t)r0 * HSTR + col] = (_Float16)(pv[r] * fast_tanh(acc[ct][r] + bv));
            }
        }
    } else {
        float p[4][10];
#pragma unroll
        for (int r = 0; r < 4; ++r)
#pragma unroll
            for (int j = 0; j < 10; ++j) p[r][j] = 0.f;
#pragma unroll
        for (int ct = 0; ct < 7; ++ct) {
            int col = cb + ct * 16 + lrow;
            bool cok = col < 220;
            float bv = cok ? bias[col] : 0.f;
            float w3v[10];
            if (cok) {
                const float2* wp = (const float2*)&W3[col * 10];
#pragma unroll
                for (int j2 = 0; j2 < 5; ++j2) {
                    float2 t = wp[j2];
                    w3v[2 * j2] = t.x;
                    w3v[2 * j2 + 1] = t.y;
                }
            } else {
#pragma unroll
                for (int j = 0; j < 10; ++j) w3v[j] = 0.f;
            }
#pragma unroll
            for (int r = 0; r < 4; ++r) {
                float h2 = pv[r] * fast_tanh(acc[ct][r] + bv);
#pragma unroll
                for (int j = 0; j < 10; ++j) p[r][j] += h2 * w3v[j];
            }
        }
        // reduce over the 16 lanes (same q) sharing each row
#pragma unroll
        for (int r = 0; r < 4; ++r)
#pragma unroll
            for (int j = 0; j < 10; ++j) {
                float vv = p[r][j];
                vv += __shfl_xor(vv, 1, 64);
                vv += __shfl_xor(vv, 2, 64);
                vv += __shfl_xor(vv, 4, 64);
                vv += __shfl_xor(vv, 8, 64);
                p[r][j] = vv;
            }
        if (lrow == 0) {
#pragma unroll
            for (int r = 0; r < 4; ++r) {
                int row = prow(q * 4 + r);
                if (row < N_NODES) {
                    float* tp = tmp + ((size_t)ch * NPAD + row) * 10;
#pragma unroll
                    for (int j2 = 0; j2 < 5; ++j2) {
                        float2 o = {p[r][2 * j2], p[r][2 * j2 + 1]};
                        *(float2*)&tp[2 * j2] = o;
                    }
                }
            }
        }
    }
}

// ---------------- launch ----------------

extern "C" void kernel_launch(void* const* d_in, const int* in_sizes, int n_in,
                              void* d_out, int out_size, void* d_ws, size_t ws_size,
                              hipStream_t stream) {
    const float* x  = (const float*)d_in[0];
    const float* W0 = (const float*)d_in[1];
    const float* b0 = (const float*)d_in[2];
    const float* W1 = (const float*)d_in[3];
    const float* b1 = (const float*)d_in[4];
    const float* W2 = (const float*)d_in[5];
    const float* b2 = (const float*)d_in[6];
    const float* W3 = (const float*)d_in[7];
    const float* b3 = (const float*)d_in[8];
    const int*   ei = (const int*)d_in[9];
    float* out = (float*)d_out;

    int* ws = (int*)d_ws;
    // word offsets (wt1/wt2 = 224*224 ushorts = 25088 WORDS each)
    int* ecsbuf     = ws + 0;               // 50432 (50178 used; [0]=0)
    int* deg_out    = ws + 50432;           // 50176
    int* bsumA      = ws + 100608;          // 256 (196 used)
    float* inv_out  = (float*)(ws + 100864);
    float* inv_in   = (float*)(ws + 151040);
    int* src_sorted = ws + 201216;          // 800000
    unsigned short* wt0h = (unsigned short*)(ws + 1001216);   // 3584 w
    unsigned short* wt0l = (unsigned short*)(ws + 1004800);   // 3584 w
    unsigned short* wt1h = (unsigned short*)(ws + 1008384);   // 25088 w
    unsigned short* wt1l = (unsigned short*)(ws + 1033472);   // 25088 w
    unsigned short* wt2h = (unsigned short*)(ws + 1058560);   // 25088 w
    unsigned short* wt2l = (unsigned short*)(ws + 1083648);   // 25088 w
    unsigned short* ahi  = (unsigned short*)(ws + 1108736);   // 5619712 w
    unsigned short* alo  = (unsigned short*)(ws + 6728448);   // 5619712 w
    _Float16* hbuf = (_Float16*)(ws + 12348160); // 50000*224 halfs = 2800000 w
    float* tmp10 = (float*)(ws + 17948160); // 2*NPAD*10 = 1003520 w -> end 18951680
    // aliases in regions not yet live at CSR-build time:
    int* rank  = (int*)ahi;                          // ahi words [0, 800000)
    int* cnt8  = (int*)alo;                          // alo words [0, 401408)
    int* deg8  = (int*)alo + 8 * NPAD;               // alo words [401408, 802816)
    float* xs  = (float*)(ws + 1108736 + 3000000);   // clear of rank & A22 region

    // zero the 8-way histogram copies (cnt8+deg8 contiguous, 3.2 MB)
    hipMemsetAsync(cnt8, 0, (size_t)16 * NPAD * sizeof(int), stream);

    // CSR hist(+rank, 8-way split) fused with weight splits
    k_hist_wsplit<<<1202, 256, 0, stream>>>(ei, deg8, cnt8, rank,
                                            W0, W1, W2, wt0h, wt0l, wt1h, wt1l, wt2h, wt2l);
    k_sum8<<<196, 256, 0, stream>>>(cnt8, deg8, ecsbuf, deg_out);
    k_scan1<<<196, 256, 0, stream>>>(ecsbuf + 1, ecsbuf + 1, bsumA, NPAD);
    k_scan_mid<<<1, 256, 0, stream>>>(bsumA, 196);
    k_scan3<<<196, 256, 0, stream>>>(ecsbuf + 1, bsumA, NPAD);
    k_post_scan<<<5470, 256, 0, stream>>>(ei, ecsbuf, rank, cnt8, deg_out, x,
                                          inv_out, inv_in, src_sorted, xs);

    int gemm_grid = (NPAD / 64) * 2;         // 1568 (both mappings)
    int agg_grid  = (N_NODES + 3) / 4;       // 12500

    // ---- layer 0
    k_agg22_split<<<(N_NODES * 16 + 255) / 256, 256, 0, stream>>>(
        xs, ecsbuf, src_sorted, inv_in, ahi, alo);
    k_gemm_mfma<1, 32, false><<<gemm_grid, 256, 0, stream>>>(
        ahi, alo, wt0h, wt0l, b0, inv_out, hbuf, nullptr, nullptr);

    // ---- layer 1
    k_agg220_split<<<agg_grid, 256, 0, stream>>>(hbuf, ecsbuf, src_sorted, inv_in, ahi, alo);
    k_gemm_mfma<7, 224, false><<<gemm_grid, 256, 0, stream>>>(
        ahi, alo, wt1h, wt1l, b1, inv_out, hbuf, nullptr, nullptr);

    // ---- layer 2 (+ fused W3 projection; h2 never materialized)
    k_agg220_split<<<agg_grid, 256, 0, stream>>>(hbuf, ecsbuf, src_sorted, inv_in, ahi, alo);
    k_gemm_mfma<7, 224, true><<<gemm_grid, 256, 0, stream>>>(
        ahi, alo, wt2h, wt2l, b2, inv_out, nullptr, W3, tmp10);

    // ---- layer 3
    k_agg10_epi<<<(N_NODES * 5 + 255) / 256, 256, 0, stream>>>(
        tmp10, ecsbuf, src_sorted, inv_in, b3, out);
}

// Round 11
// 431.282 us; speedup vs baseline: 1.4636x; 1.0764x over previous
//
#include <hip/hip_runtime.h>
#include <math.h>

#define N_NODES 50000
#define N_EDGES 800000
#define NPAD 50176
#define HSTR 224   // hbuf row stride in HALFS: 448 B = exactly 4 x 128B sectors per row fetch
#define RBIN 12544 // bins per histogram range (NPAD/4), 49 KB LDS as int
#define NCHK 32    // edge chunks; chunk = 25000 edges
// ecsbuf (NPAD+2 ints): after k_sum32, ecsbuf[1+d] = total in-degree count;
// after scans, ecsbuf[1+d] = start(d). Readers: start(n)=ecsbuf[n+1], end=ecsbuf[n+2].
// CSR build has ZERO global atomics (r7: global atomic stream is ~22G/s
// throughput-bound at the coherence point; r8: LDS hist with R=49 ranges was
// 49x read-amplified — fix is R=4 ranges x C=32 chunks, amp=4, 256 hist blocks):
// dst job: per-(range,chunk) block LDS-counts its bins, RETURNING ds_add gives
// local rank; rank[e] = (lr<<5)|chunk. src job: same, non-returning, -> deg_part.
// k_sum32 folds 32 chunk-partials -> totals + in-place exclusive chunk-prefix
// (cnt_part becomes prefix); fill: pos = start(d) + prefix[chunk][d] + lr.

typedef __attribute__((ext_vector_type(8))) short short8;
typedef __attribute__((ext_vector_type(4))) float f32x4;
typedef __attribute__((ext_vector_type(4))) _Float16 half4;

// ---------------- helpers ----------------

__device__ __forceinline__ float fast_tanh(float x) {
    float e = __expf(2.0f * x);
    float r = __builtin_amdgcn_rcpf(e + 1.0f);
    return 1.0f - 2.0f * r;
}

__device__ __forceinline__ unsigned short rne_bf16(float x) {
    unsigned u = __builtin_bit_cast(unsigned, x);
    return (unsigned short)((u + 0x7FFFu + ((u >> 16) & 1u)) >> 16);
}

__device__ __forceinline__ void split_bf16(float x, unsigned short& hi, unsigned short& lo) {
    hi = rne_bf16(x);
    float hf = __builtin_bit_cast(float, (unsigned)hi << 16);
    lo = rne_bf16(x - hf);
}

__device__ __forceinline__ f32x4 mfma16(short8 a, short8 b, f32x4 c) {
    return __builtin_amdgcn_mfma_f32_16x16x32_bf16(a, b, c, 0, 0, 0);
}

__device__ __forceinline__ void wsplit_one(const float* __restrict__ W, int KIN, int LDA,
                                           unsigned short* __restrict__ WT_hi,
                                           unsigned short* __restrict__ WT_lo, int idx) {
    int n = idx / LDA;
    int k = idx - n * LDA;
    float v = (n < 220 && k < KIN) ? W[k * 220 + n] : 0.f;
    unsigned short hi, lo;
    split_bf16(v, hi, lo);
    WT_hi[idx] = hi;
    WT_lo[idx] = lo;
}

// ---------------- CSR build (zero global atomics) ----------------

// partitioned launch:
// [0,128)    dst rank job: rng = bx>>5, chk = bx&31 (4 ranges x 32 chunks)
// [128,256)  src hist job: same decomposition
// [256,284)  wsplit W0 | [284,480) W1 | [480,676) W2
__global__ void k_build(const int* __restrict__ ei, int* __restrict__ deg_part,
                        int* __restrict__ cnt_part, int* __restrict__ rank,
                        const float* __restrict__ W0, const float* __restrict__ W1,
                        const float* __restrict__ W2,
                        unsigned short* __restrict__ wt0h, unsigned short* __restrict__ wt0l,
                        unsigned short* __restrict__ wt1h, unsigned short* __restrict__ wt1l,
                        unsigned short* __restrict__ wt2h, unsigned short* __restrict__ wt2l) {
    __shared__ int hb[RBIN];   // 49 KB -> 3 blocks/CU
    int bx = blockIdx.x;
    if (bx < 128) {
        int rng = bx >> 5, chk = bx & 31;
        int lo = rng * RBIN;
        for (int i = threadIdx.x; i < RBIN; i += 256) hb[i] = 0;
        __syncthreads();
        int ebeg = chk * 25000, eend = ebeg + 25000;
        for (int e = ebeg + threadIdx.x; e < eend; e += 256) {
            int d = ei[N_EDGES + e];
            unsigned idx = (unsigned)(d - lo);
            if (idx < (unsigned)RBIN) {
                int lr = atomicAdd(&hb[idx], 1);     // LDS returning add
                rank[e] = (lr << 5) | chk;
            }
        }
        __syncthreads();
        for (int i = threadIdx.x; i < RBIN; i += 256)
            cnt_part[chk * NPAD + lo + i] = hb[i];
    } else if (bx < 256) {
        int b2 = bx - 128;
        int rng = b2 >> 5, chk = b2 & 31;
        int lo = rng * RBIN;
        for (int i = threadIdx.x; i < RBIN; i += 256) hb[i] = 0;
        __syncthreads();
        int ebeg = chk * 25000, eend = ebeg + 25000;
        for (int e = ebeg + threadIdx.x; e < eend; e += 256) {
            int s = ei[e];
            unsigned idx = (unsigned)(s - lo);
            if (idx < (unsigned)RBIN) atomicAdd(&hb[idx], 1);
        }
        __syncthreads();
        for (int i = threadIdx.x; i < RBIN; i += 256)
            deg_part[chk * NPAD + lo + i] = hb[i];
    } else if (bx < 284) {
        int idx = (bx - 256) * 256 + threadIdx.x;           // 224*32 = 7168
        if (idx < 224 * 32) wsplit_one(W0, 22, 32, wt0h, wt0l, idx);
    } else if (bx < 480) {
        int idx = (bx - 284) * 256 + threadIdx.x;           // 224*224 = 50176
        wsplit_one(W1, 220, 224, wt1h, wt1l, idx);
    } else {
        int idx = (bx - 480) * 256 + threadIdx.x;
        wsplit_one(W2, 220, 224, wt2h, wt2l, idx);
    }
}

// fold 32 chunk-partials: cnt_part -> in-place exclusive per-bin prefix,
// ecsbuf[1+d] = total in-degree, deg_out[d] = total out-degree.
// All outputs fully written -> no pre-memset anywhere.
__global__ void k_sum32(int* __restrict__ cnt_part, const int* __restrict__ deg_part,
                        int* __restrict__ ecsbuf, int* __restrict__ deg_out) {
    int d = blockIdx.x * 256 + threadIdx.x;
    if (d >= NPAD) return;
    int s = 0;
#pragma unroll
    for (int c = 0; c < NCHK; ++c) {
        int v = cnt_part[c * NPAD + d];
        cnt_part[c * NPAD + d] = s;
        s += v;
    }
    ecsbuf[1 + d] = s;
    if (d == 0) ecsbuf[0] = 0;
    int t = 0;
#pragma unroll
    for (int c = 0; c < NCHK; ++c) t += deg_part[c * NPAD + d];
    deg_out[d] = t;
}

__global__ void k_scan1(const int* __restrict__ in, int* __restrict__ out,
                        int* __restrict__ bsum, int n) {
    __shared__ int s[256];
    int i = blockIdx.x * 256 + threadIdx.x;
    int v = (i < n) ? in[i] : 0;
    s[threadIdx.x] = v;
    __syncthreads();
    for (int off = 1; off < 256; off <<= 1) {
        int t = (threadIdx.x >= off) ? s[threadIdx.x - off] : 0;
        __syncthreads();
        s[threadIdx.x] += t;
        __syncthreads();
    }
    if (i < n) out[i] = s[threadIdx.x] - v;   // exclusive
    if (threadIdx.x == 255 && bsum) bsum[blockIdx.x] = s[255];
}

__global__ void k_scan_mid(int* __restrict__ a, int n) {
    __shared__ int s[256];
    __shared__ int carry;
    if (threadIdx.x == 0) carry = 0;
    for (int base = 0; base < n; base += 256) {
        int i = base + threadIdx.x;
        int v = (i < n) ? a[i] : 0;
        s[threadIdx.x] = v;
        __syncthreads();
        for (int off = 1; off < 256; off <<= 1) {
            int t = (threadIdx.x >= off) ? s[threadIdx.x - off] : 0;
            __syncthreads();
            s[threadIdx.x] += t;
            __syncthreads();
        }
        int c = carry;
        if (i < n) a[i] = s[threadIdx.x] - v + c;
        __syncthreads();
        if (threadIdx.x == 0) carry = c + s[255];
        __syncthreads();
    }
}

__global__ void k_scan3(int* __restrict__ out, const int* __restrict__ bscan, int n) {
    int i = blockIdx.x * 256 + threadIdx.x;
    if (i < n) out[i] += bscan[blockIdx.x];
}

// fused post-scan: [0,196) invsqrt | [196,3321) atomic-free fill | [3321,5470) prescale xs
__global__ void k_post_scan(const int* __restrict__ ei, const int* __restrict__ ecsbuf,
                            const int* __restrict__ rank, const int* __restrict__ prefix,
                            const int* __restrict__ deg_out, const float* __restrict__ x,
                            float* __restrict__ inv_out, float* __restrict__ inv_in,
                            int* __restrict__ src_sorted, float* __restrict__ xs) {
    int bx = blockIdx.x;
    if (bx < 196) {
        int n = bx * 256 + threadIdx.x;
        if (n >= N_NODES) return;
        int di = ecsbuf[n + 2] - ecsbuf[n + 1];
        int a = deg_out[n]; if (a < 1) a = 1;
        if (di < 1) di = 1;
        inv_out[n] = 1.0f / sqrtf((float)a);
        inv_in[n]  = 1.0f / sqrtf((float)di);
    } else if (bx < 3321) {
        int e = (bx - 196) * 256 + threadIdx.x;
        if (e < N_EDGES) {
            int d = ei[N_EDGES + e];
            int rc = rank[e];
            int c = rc & 31, r = rc >> 5;
            src_sorted[ecsbuf[1 + d] + prefix[c * NPAD + d] + r] = ei[e];
        }
    } else {
        int idx = (bx - 3321) * 256 + threadIdx.x;   // n*11 + f2
        if (idx >= N_NODES * 11) return;
        int n = idx / 11;
        int f2 = idx - n * 11;
        int a = deg_out[n]; if (a < 1) a = 1;
        float sc = 1.0f / sqrtf((float)a);
        float2 v = *(const float2*)&x[n * 22 + f2 * 2];
        v.x *= sc; v.y *= sc;
        *(float2*)&xs[n * 22 + f2 * 2] = v;
    }
}

// ---------------- aggregation ----------------

// layer 0: gather pre-scaled xs (width 22), *inv_in, split to bf16 A (K pad 32).
__global__ void k_agg22_split(const float* __restrict__ xs,
                              const int* __restrict__ ecsbuf, const int* __restrict__ srcs,
                              const float* __restrict__ inv_in,
                              unsigned short* __restrict__ A_hi, unsigned short* __restrict__ A_lo) {
    int idx = blockIdx.x * 256 + threadIdx.x;
    int n = idx >> 4, f2 = idx & 15;
    if (n >= N_NODES) return;
    float ax = 0.f, ay = 0.f;
    if (f2 <= 10) {
        const float2* xb = (const float2*)(xs) + f2;
        int e = ecsbuf[n + 1], end = ecsbuf[n + 2];
        for (; e + 3 < end; e += 4) {
            int s0 = srcs[e], s1 = srcs[e + 1], s2 = srcs[e + 2], s3 = srcs[e + 3];
            float2 v0 = xb[s0 * 11], v1 = xb[s1 * 11];
            float2 v2 = xb[s2 * 11], v3 = xb[s3 * 11];
            ax += (v0.x + v1.x) + (v2.x + v3.x);
            ay += (v0.y + v1.y) + (v2.y + v3.y);
        }
        for (; e < end; ++e) {
            float2 v0 = xb[srcs[e] * 11];
            ax += v0.x;
            ay += v0.y;
        }
        float si = inv_in[n];
        ax *= si; ay *= si;
    }
    ushort2 h2, l2;
    split_bf16(ax, h2.x, l2.x);
    split_bf16(ay, h2.y, l2.y);
    *(ushort2*)&A_hi[n * 32 + f2 * 2] = h2;
    *(ushort2*)&A_lo[n * 32 + f2 * 2] = l2;
}

// width-220 gather (h stored fp16, row = 224 halfs = 448 B = 4 sectors) + *inv_in
// -> split bf16 A.  One node per 64-lane group; lanes 0..54 own 4 features
// (8 B half4 loads); 8 loads in flight; fp32 accumulation.
__global__ __launch_bounds__(256) void k_agg220_split(const _Float16* __restrict__ h,
                                                      const int* __restrict__ ecsbuf,
                                                      const int* __restrict__ srcs,
                                                      const float* __restrict__ inv_in,
                                                      unsigned short* __restrict__ A_hi,
                                                      unsigned short* __restrict__ A_lo) {
    int lane = threadIdx.x & 63;
    int n = blockIdx.x * 4 + (threadIdx.x >> 6);
    if (n >= N_NODES || lane >= 56) return;   // no barriers; early-exit safe
    size_t ob = (size_t)n * 224 + lane * 4;
    if (lane == 55) {                          // K-pad columns 220..223 = 0
        ushort4 z = {0, 0, 0, 0};
        *(ushort4*)&A_hi[ob] = z;
        *(ushort4*)&A_lo[ob] = z;
        return;
    }
    int f4 = lane * 4;
    const _Float16* hb = h + f4;
    int e = ecsbuf[n + 1], end = ecsbuf[n + 2];
    float4 a0 = {0,0,0,0}, a1 = {0,0,0,0}, a2 = {0,0,0,0}, a3 = {0,0,0,0};
    for (; e + 7 < end; e += 8) {
        int s0 = srcs[e],     s1 = srcs[e + 1], s2 = srcs[e + 2], s3 = srcs[e + 3];
        int s4 = srcs[e + 4], s5 = srcs[e + 5], s6 = srcs[e + 6], s7 = srcs[e + 7];
        half4 v0 = *(const half4*)(hb + (size_t)s0 * HSTR);
        half4 v1 = *(const half4*)(hb + (size_t)s1 * HSTR);
        half4 v2 = *(const half4*)(hb + (size_t)s2 * HSTR);
        half4 v3 = *(const half4*)(hb + (size_t)s3 * HSTR);
        half4 v4 = *(const half4*)(hb + (size_t)s4 * HSTR);
        half4 v5 = *(const half4*)(hb + (size_t)s5 * HSTR);
        half4 v6 = *(const half4*)(hb + (size_t)s6 * HSTR);
        half4 v7 = *(const half4*)(hb + (size_t)s7 * HSTR);
        a0.x += (float)v0.x; a0.y += (float)v0.y; a0.z += (float)v0.z; a0.w += (float)v0.w;
        a1.x += (float)v1.x; a1.y += (float)v1.y; a1.z += (float)v1.z; a1.w += (float)v1.w;
        a2.x += (float)v2.x; a2.y += (float)v2.y; a2.z += (float)v2.z; a2.w += (float)v2.w;
        a3.x += (float)v3.x; a3.y += (float)v3.y; a3.z += (float)v3.z; a3.w += (float)v3.w;
        a0.x += (float)v4.x; a0.y += (float)v4.y; a0.z += (float)v4.z; a0.w += (float)v4.w;
        a1.x += (float)v5.x; a1.y += (float)v5.y; a1.z += (float)v5.z; a1.w += (float)v5.w;
        a2.x += (float)v6.x; a2.y += (float)v6.y; a2.z += (float)v6.z; a2.w += (float)v6.w;
        a3.x += (float)v7.x; a3.y += (float)v7.y; a3.z += (float)v7.z; a3.w += (float)v7.w;
    }
    for (; e + 3 < end; e += 4) {
        int s0 = srcs[e], s1 = srcs[e + 1], s2 = srcs[e + 2], s3 = srcs[e + 3];
        half4 v0 = *(const half4*)(hb + (size_t)s0 * HSTR);
        half4 v1 = *(const half4*)(hb + (size_t)s1 * HSTR);
        half4 v2 = *(const half4*)(hb + (size_t)s2 * HSTR);
        half4 v3 = *(const half4*)(hb + (size_t)s3 * HSTR);
        a0.x += (float)v0.x; a0.y += (float)v0.y; a0.z += (float)v0.z; a0.w += (float)v0.w;
        a1.x += (float)v1.x; a1.y += (float)v1.y; a1.z += (float)v1.z; a1.w += (float)v1.w;
        a2.x += (float)v2.x; a2.y += (float)v2.y; a2.z += (float)v2.z; a2.w += (float)v2.w;
        a3.x += (float)v3.x; a3.y += (float)v3.y; a3.z += (float)v3.z; a3.w += (float)v3.w;
    }
    for (; e < end; ++e) {
        half4 v = *(const half4*)(hb + (size_t)srcs[e] * HSTR);
        a0.x += (float)v.x; a0.y += (float)v.y; a0.z += (float)v.z; a0.w += (float)v.w;
    }
    float sc = inv_in[n];
    float4 t;
    t.x = ((a0.x + a1.x) + (a2.x + a3.x)) * sc;
    t.y = ((a0.y + a1.y) + (a2.y + a3.y)) * sc;
    t.z = ((a0.z + a1.z) + (a2.z + a3.z)) * sc;
    t.w = ((a0.w + a1.w) + (a2.w + a3.w)) * sc;
    ushort4 h4, l4;
    split_bf16(t.x, h4.x, l4.x);
    split_bf16(t.y, h4.y, l4.y);
    split_bf16(t.z, h4.z, l4.z);
    split_bf16(t.w, h4.w, l4.w);
    *(ushort4*)&A_hi[ob] = h4;
    *(ushort4*)&A_lo[ob] = l4;
}

// layer 3: gather tmp10 halves (width 10 x 2, 4 MB -> L2-resident), *inv_in + bias
__global__ void k_agg10_epi(const float* __restrict__ tmp, const int* __restrict__ ecsbuf,
                            const int* __restrict__ srcs, const float* __restrict__ inv_in,
                            const float* __restrict__ bias, float* __restrict__ out) {
    int idx = blockIdx.x * 256 + threadIdx.x;
    if (idx >= N_NODES * 5) return;
    int n = idx / 5;
    int f2 = idx - n * 5;
    const float2* tb0 = (const float2*)(tmp) + f2;
    const float2* tb1 = (const float2*)(tmp + (size_t)NPAD * 10) + f2;
    float ax = 0.f, ay = 0.f;
    int e = ecsbuf[n + 1], end = ecsbuf[n + 2];
    for (; e + 1 < end; e += 2) {
        float2 u0 = tb0[srcs[e] * 5],     w0 = tb1[srcs[e] * 5];
        float2 u1 = tb0[srcs[e + 1] * 5], w1 = tb1[srcs[e + 1] * 5];
        ax += (u0.x + w0.x) + (u1.x + w1.x);
        ay += (u0.y + w0.y) + (u1.y + w1.y);
    }
    if (e < end) {
        float2 u0 = tb0[srcs[e] * 5], w0 = tb1[srcs[e] * 5];
        ax += u0.x + w0.x;
        ay += u0.y + w0.y;
    }
    float si = inv_in[n];
    float2 o;
    o.x = ax * si + bias[f2 * 2];
    o.y = ay * si + bias[f2 * 2 + 1];
    *(float2*)&out[n * 10 + f2 * 2] = o;
}

// ---------------- MFMA split-bf16 GEMM (r4 shape + XCD-aligned rows) ---------
// D = A@W via A_hi*W_hi + A_hi*W_lo + A_lo*W_hi (~fp32 precision).
// Wave = 16 rows x 112 cols (acc[7] = 28 VGPR, no spill at (256,4)).
// Block = 4 waves = 64 rows x one col-half; grid 1568.
// XCD alignment (LDA==224 only): row(i) = 4s + 512v + 32*(4w + i/4) + i%4 with
// s=bid&7, ch=(bid>>3)&1, v=bid>>4 (verified bijective + passing, r8/r10).
template <int KSTEPS, int LDA, bool FUSE_W3>
__global__ __launch_bounds__(256, 4) void k_gemm_mfma(const unsigned short* __restrict__ A_hi,
                                                      const unsigned short* __restrict__ A_lo,
                                                      const unsigned short* __restrict__ WT_hi,
                                                      const unsigned short* __restrict__ WT_lo,
                                                      const float* __restrict__ bias,
                                                      const float* __restrict__ post,
                                                      _Float16* __restrict__ out,
                                                      const float* __restrict__ W3,
                                                      float* __restrict__ tmp) {
    constexpr bool SWZ = (LDA == 224);
    int tid = threadIdx.x;
    int l = tid & 63, w = tid >> 6;
    int lrow = l & 15, q = l >> 4;
    int bid = blockIdx.x;

    int ch, s = 0, v = 0, rt = 0;
    if constexpr (SWZ) {
        s = bid & 7;
        int u = bid >> 3;
        ch = u & 1;
        v = u >> 1;                 // [0,98)
    } else {
        ch = bid & 1;
        rt = (bid >> 1) * 64 + w * 16;
    }
    int cb = ch * 112;

    // logical tile row i (0..15) -> physical A/out row
    auto prow = [&](int i) -> int {
        if constexpr (SWZ) return 4 * s + 512 * v + 32 * (4 * w + (i >> 2)) + (i & 3);
        else return rt + i;
    };

    int arow = prow(lrow);
    const unsigned short* pah = A_hi + (size_t)arow * LDA + q * 8;
    const unsigned short* pal = A_lo + (size_t)arow * LDA + q * 8;
    const unsigned short* pbh = WT_hi + (size_t)(cb + lrow) * LDA + q * 8;
    const unsigned short* pbl = WT_lo + (size_t)(cb + lrow) * LDA + q * 8;

    f32x4 acc[7];
#pragma unroll
    for (int ct = 0; ct < 7; ++ct) acc[ct] = (f32x4){0.f, 0.f, 0.f, 0.f};

#pragma unroll
    for (int ks = 0; ks < KSTEPS; ++ks) {
        int k0 = ks * 32;
        short8 ah = *(const short8*)(const void*)(pah + k0);
        short8 al = *(const short8*)(const void*)(pal + k0);
#pragma unroll
        for (int ct = 0; ct < 7; ++ct) {
            size_t boff = (size_t)(ct * 16) * LDA + k0;
            short8 bh = *(const short8*)(const void*)(pbh + boff);
            short8 bl = *(const short8*)(const void*)(pbl + boff);
            acc[ct] = mfma16(ah, bh, acc[ct]);
            acc[ct] = mfma16(ah, bl, acc[ct]);
            acc[ct] = mfma16(al, bh, acc[ct]);
        }
    }

    float pv[4];
#pragma unroll
    for (int r = 0; r < 4; ++r) {
        int r0 = prow(q * 4 + r);
        pv[r] = (r0 < N_NODES) ? post[r0] : 0.f;
    }

    if (!FUSE_W3) {
#pragma unroll
        for (int ct = 0; ct < 7; ++ct) {
            int col = cb + ct * 16 + lrow;
            if (col >= 220) continue;
            float bv = bias[col];
#pragma unroll
            for (int r = 0; r < 4; ++r) {
                int r0 = prow(q * 4 + r);
                if (r0 < N_NODES)
                    out[(size_t)r0 * HSTR + col] = (_Float16)(pv[r] * fast_tanh(acc[ct][r] + bv));
            }
        }
    } else {
        float p[4][10];
#pragma unroll
        for (int r = 0; r < 4; ++r)
#pragma unroll
            for (int j = 0; j < 10; ++j) p[r][j] = 0.f;
#pragma unroll
        for (int ct = 0; ct < 7; ++ct) {
            int col = cb + ct * 16 + lrow;
            bool cok = col < 220;
            float bv = cok ? bias[col] : 0.f;
            float w3v[10];
            if (cok) {
                const float2* wp = (const float2*)&W3[col * 10];
#pragma unroll
                for (int j2 = 0; j2 < 5; ++j2) {
                    float2 t = wp[j2];
                    w3v[2 * j2] = t.x;
                    w3v[2 * j2 + 1] = t.y;
                }
            } else {
#pragma unroll
                for (int j = 0; j < 10; ++j) w3v[j] = 0.f;
            }
#pragma unroll
            for (int r = 0; r < 4; ++r) {
                float h2 = pv[r] * fast_tanh(acc[ct][r] + bv);
#pragma unroll
                for (int j = 0; j < 10; ++j) p[r][j] += h2 * w3v[j];
            }
        }
        // reduce over the 16 lanes (same q) sharing each row
#pragma unroll
        for (int r = 0; r < 4; ++r)
#pragma unroll
            for (int j = 0; j < 10; ++j) {
                float vv = p[r][j];
                vv += __shfl_xor(vv, 1, 64);
                vv += __shfl_xor(vv, 2, 64);
                vv += __shfl_xor(vv, 4, 64);
                vv += __shfl_xor(vv, 8, 64);
                p[r][j] = vv;
            }
        if (lrow == 0) {
#pragma unroll
            for (int r = 0; r < 4; ++r) {
                int row = prow(q * 4 + r);
                if (row < N_NODES) {
                    float* tp = tmp + ((size_t)ch * NPAD + row) * 10;
#pragma unroll
                    for (int j2 = 0; j2 < 5; ++j2) {
                        float2 o = {p[r][2 * j2], p[r][2 * j2 + 1]};
                        *(float2*)&tp[2 * j2] = o;
                    }
                }
            }
        }
    }
}

// ---------------- launch ----------------

extern "C" void kernel_launch(void* const* d_in, const int* in_sizes, int n_in,
                              void* d_out, int out_size, void* d_ws, size_t ws_size,
                              hipStream_t stream) {
    const float* x  = (const float*)d_in[0];
    const float* W0 = (const float*)d_in[1];
    const float* b0 = (const float*)d_in[2];
    const float* W1 = (const float*)d_in[3];
    const float* b1 = (const float*)d_in[4];
    const float* W2 = (const float*)d_in[5];
    const float* b2 = (const float*)d_in[6];
    const float* W3 = (const float*)d_in[7];
    const float* b3 = (const float*)d_in[8];
    const int*   ei = (const int*)d_in[9];
    float* out = (float*)d_out;

    int* ws = (int*)d_ws;
    // word offsets (wt1/wt2 = 224*224 ushorts = 25088 WORDS each)
    int* ecsbuf     = ws + 0;               // 50432 (50178 used; [0]=0)
    int* deg_out    = ws + 50432;           // 50176
    int* bsumA      = ws + 100608;          // 256 (196 used)
    float* inv_out  = (float*)(ws + 100864);
    float* inv_in   = (float*)(ws + 151040);
    int* src_sorted = ws + 201216;          // 800000
    unsigned short* wt0h = (unsigned short*)(ws + 1001216);   // 3584 w
    unsigned short* wt0l = (unsigned short*)(ws + 1004800);   // 3584 w
    unsigned short* wt1h = (unsigned short*)(ws + 1008384);   // 25088 w
    unsigned short* wt1l = (unsigned short*)(ws + 1033472);   // 25088 w
    unsigned short* wt2h = (unsigned short*)(ws + 1058560);   // 25088 w
    unsigned short* wt2l = (unsigned short*)(ws + 1083648);   // 25088 w
    unsigned short* ahi  = (unsigned short*)(ws + 1108736);   // 5619712 w
    unsigned short* alo  = (unsigned short*)(ws + 6728448);   // 5619712 w
    _Float16* hbuf = (_Float16*)(ws + 12348160); // 50000*224 halfs = 2800000 w
    float* tmp10 = (float*)(ws + 17948160); // 2*NPAD*10 = 1003520 w -> end 18951680
    // aliases in regions not yet live at CSR-build time:
    int* rank     = (int*)ahi;                        // ahi words [0, 800000)
    int* cnt_part = (int*)alo;                        // alo words [0, 1605632)
    int* deg_part = (int*)alo + NCHK * NPAD;          // alo words [1605632, 3211264)
    float* xs = (float*)(ws + 1108736 + 3000000);     // clear of rank & A22 region

    // CSR build: zero global atomics (LDS hist jobs fully overwrite partials)
    k_build<<<676, 256, 0, stream>>>(ei, deg_part, cnt_part, rank,
                                     W0, W1, W2, wt0h, wt0l, wt1h, wt1l, wt2h, wt2l);
    k_sum32<<<196, 256, 0, stream>>>(cnt_part, deg_part, ecsbuf, deg_out);
    k_scan1<<<196, 256, 0, stream>>>(ecsbuf + 1, ecsbuf + 1, bsumA, NPAD);
    k_scan_mid<<<1, 256, 0, stream>>>(bsumA, 196);
    k_scan3<<<196, 256, 0, stream>>>(ecsbuf + 1, bsumA, NPAD);
    k_post_scan<<<5470, 256, 0, stream>>>(ei, ecsbuf, rank, cnt_part, deg_out, x,
                                          inv_out, inv_in, src_sorted, xs);

    int gemm_grid = (NPAD / 64) * 2;         // 1568 (both mappings)
    int agg_grid  = (N_NODES + 3) / 4;       // 12500

    // ---- layer 0
    k_agg22_split<<<(N_NODES * 16 + 255) / 256, 256, 0, stream>>>(
        xs, ecsbuf, src_sorted, inv_in, ahi, alo);
    k_gemm_mfma<1, 32, false><<<gemm_grid, 256, 0, stream>>>(
        ahi, alo, wt0h, wt0l, b0, inv_out, hbuf, nullptr, nullptr);

    // ---- layer 1
    k_agg220_split<<<agg_grid, 256, 0, stream>>>(hbuf, ecsbuf, src_sorted, inv_in, ahi, alo);
    k_gemm_mfma<7, 224, false><<<gemm_grid, 256, 0, stream>>>(
        ahi, alo, wt1h, wt1l, b1, inv_out, hbuf, nullptr, nullptr);

    // ---- layer 2 (+ fused W3 projection; h2 never materialized)
    k_agg220_split<<<agg_grid, 256, 0, stream>>>(hbuf, ecsbuf, src_sorted, inv_in, ahi, alo);
    k_gemm_mfma<7, 224, true><<<gemm_grid, 256, 0, stream>>>(
        ahi, alo, wt2h, wt2l, b2, inv_out, nullptr, W3, tmp10);

    // ---- layer 3
    k_agg10_epi<<<(N_NODES * 5 + 255) / 256, 256, 0, stream>>>(
        tmp10, ecsbuf, src_sorted, inv_in, b3, out);
}

// Round 12
// 422.203 us; speedup vs baseline: 1.4950x; 1.0215x over previous
//
#include <hip/hip_runtime.h>
#include <math.h>

#define N_NODES 50000
#define N_EDGES 800000
#define NPAD 50176
#define HSTR 224   // hbuf row stride in HALFS: 448 B = exactly 4 x 128B sectors per row fetch
#define RBIN 12544 // bins per histogram range (NPAD/4), 49 KB LDS as int
#define NCHK 32    // edge chunks; chunk = 25000 edges
// ecsbuf (NPAD+2 ints): after k_sum32, ecsbuf[1+d] = total in-degree count;
// after scans, ecsbuf[1+d] = start(d). Readers: start(n)=ecsbuf[n+1], end=ecsbuf[n+2].
// CSR build: ZERO global atomics (r7: atomic stream ~22G/s coherence-bound;
// r11: 4 ranges x 32 chunks LDS hist = win, k_build ~25us).
// GEMM numerics (r12): A in SINGLE fp16 (one rounding, same error class as the
// fp16 hbuf storage that measurably left absmax pinned at 1.5e-5), W in
// split-fp16 hi+lo (reconstructs W to ~2^-22, better than old split-bf16),
// f16 MFMA: D = A*(Whi) + A*(Wlo). A bytes halve everywhere; 2 MFMA not 3.

typedef __attribute__((ext_vector_type(8))) _Float16 half8;
typedef __attribute__((ext_vector_type(4))) float f32x4;
typedef __attribute__((ext_vector_type(4))) _Float16 half4;
typedef __attribute__((ext_vector_type(2))) _Float16 half2_t;

// ---------------- helpers ----------------

__device__ __forceinline__ float fast_tanh(float x) {
    float e = __expf(2.0f * x);
    float r = __builtin_amdgcn_rcpf(e + 1.0f);
    return 1.0f - 2.0f * r;
}

__device__ __forceinline__ f32x4 mfma16f(half8 a, half8 b, f32x4 c) {
    return __builtin_amdgcn_mfma_f32_16x16x32_f16(a, b, c, 0, 0, 0);
}

// split W to fp16 hi + fp16 lo (hi = RNE(v); lo = RNE(v - hi))
__device__ __forceinline__ void wsplit_one(const float* __restrict__ W, int KIN, int LDA,
                                           _Float16* __restrict__ WT_hi,
                                           _Float16* __restrict__ WT_lo, int idx) {
    int n = idx / LDA;
    int k = idx - n * LDA;
    float v = (n < 220 && k < KIN) ? W[k * 220 + n] : 0.f;
    _Float16 hi = (_Float16)v;
    _Float16 lo = (_Float16)(v - (float)hi);
    WT_hi[idx] = hi;
    WT_lo[idx] = lo;
}

// ---------------- CSR build (zero global atomics) ----------------

// partitioned launch:
// [0,128)    dst rank job: rng = bx>>5, chk = bx&31 (4 ranges x 32 chunks)
// [128,256)  src hist job: same decomposition
// [256,284)  wsplit W0 | [284,480) W1 | [480,676) W2
__global__ void k_build(const int* __restrict__ ei, int* __restrict__ deg_part,
                        int* __restrict__ cnt_part, int* __restrict__ rank,
                        const float* __restrict__ W0, const float* __restrict__ W1,
                        const float* __restrict__ W2,
                        _Float16* __restrict__ wt0h, _Float16* __restrict__ wt0l,
                        _Float16* __restrict__ wt1h, _Float16* __restrict__ wt1l,
                        _Float16* __restrict__ wt2h, _Float16* __restrict__ wt2l) {
    __shared__ int hb[RBIN];   // 49 KB -> 3 blocks/CU
    int bx = blockIdx.x;
    if (bx < 128) {
        int rng = bx >> 5, chk = bx & 31;
        int lo = rng * RBIN;
        for (int i = threadIdx.x; i < RBIN; i += 256) hb[i] = 0;
        __syncthreads();
        int ebeg = chk * 25000, eend = ebeg + 25000;
        for (int e = ebeg + threadIdx.x; e < eend; e += 256) {
            int d = ei[N_EDGES + e];
            unsigned idx = (unsigned)(d - lo);
            if (idx < (unsigned)RBIN) {
                int lr = atomicAdd(&hb[idx], 1);     // LDS returning add
                rank[e] = (lr << 5) | chk;
            }
        }
        __syncthreads();
        for (int i = threadIdx.x; i < RBIN; i += 256)
            cnt_part[chk * NPAD + lo + i] = hb[i];
    } else if (bx < 256) {
        int b2 = bx - 128;
        int rng = b2 >> 5, chk = b2 & 31;
        int lo = rng * RBIN;
        for (int i = threadIdx.x; i < RBIN; i += 256) hb[i] = 0;
        __syncthreads();
        int ebeg = chk * 25000, eend = ebeg + 25000;
        for (int e = ebeg + threadIdx.x; e < eend; e += 256) {
            int s = ei[e];
            unsigned idx = (unsigned)(s - lo);
            if (idx < (unsigned)RBIN) atomicAdd(&hb[idx], 1);
        }
        __syncthreads();
        for (int i = threadIdx.x; i < RBIN; i += 256)
            deg_part[chk * NPAD + lo + i] = hb[i];
    } else if (bx < 284) {
        int idx = (bx - 256) * 256 + threadIdx.x;           // 224*32 = 7168
        if (idx < 224 * 32) wsplit_one(W0, 22, 32, wt0h, wt0l, idx);
    } else if (bx < 480) {
        int idx = (bx - 284) * 256 + threadIdx.x;           // 224*224 = 50176
        wsplit_one(W1, 220, 224, wt1h, wt1l, idx);
    } else {
        int idx = (bx - 480) * 256 + threadIdx.x;
        wsplit_one(W2, 220, 224, wt2h, wt2l, idx);
    }
}

// fold 32 chunk-partials: cnt_part -> in-place exclusive per-bin prefix,
// ecsbuf[1+d] = total in-degree, deg_out[d] = total out-degree.
__global__ void k_sum32(int* __restrict__ cnt_part, const int* __restrict__ deg_part,
                        int* __restrict__ ecsbuf, int* __restrict__ deg_out) {
    int d = blockIdx.x * 256 + threadIdx.x;
    if (d >= NPAD) return;
    int s = 0;
#pragma unroll
    for (int c = 0; c < NCHK; ++c) {
        int v = cnt_part[c * NPAD + d];
        cnt_part[c * NPAD + d] = s;
        s += v;
    }
    ecsbuf[1 + d] = s;
    if (d == 0) ecsbuf[0] = 0;
    int t = 0;
#pragma unroll
    for (int c = 0; c < NCHK; ++c) t += deg_part[c * NPAD + d];
    deg_out[d] = t;
}

__global__ void k_scan1(const int* __restrict__ in, int* __restrict__ out,
                        int* __restrict__ bsum, int n) {
    __shared__ int s[256];
    int i = blockIdx.x * 256 + threadIdx.x;
    int v = (i < n) ? in[i] : 0;
    s[threadIdx.x] = v;
    __syncthreads();
    for (int off = 1; off < 256; off <<= 1) {
        int t = (threadIdx.x >= off) ? s[threadIdx.x - off] : 0;
        __syncthreads();
        s[threadIdx.x] += t;
        __syncthreads();
    }
    if (i < n) out[i] = s[threadIdx.x] - v;   // exclusive
    if (threadIdx.x == 255 && bsum) bsum[blockIdx.x] = s[255];
}

__global__ void k_scan_mid(int* __restrict__ a, int n) {
    __shared__ int s[256];
    __shared__ int carry;
    if (threadIdx.x == 0) carry = 0;
    for (int base = 0; base < n; base += 256) {
        int i = base + threadIdx.x;
        int v = (i < n) ? a[i] : 0;
        s[threadIdx.x] = v;
        __syncthreads();
        for (int off = 1; off < 256; off <<= 1) {
            int t = (threadIdx.x >= off) ? s[threadIdx.x - off] : 0;
            __syncthreads();
            s[threadIdx.x] += t;
            __syncthreads();
        }
        int c = carry;
        if (i < n) a[i] = s[threadIdx.x] - v + c;
        __syncthreads();
        if (threadIdx.x == 0) carry = c + s[255];
        __syncthreads();
    }
}

__global__ void k_scan3(int* __restrict__ out, const int* __restrict__ bscan, int n) {
    int i = blockIdx.x * 256 + threadIdx.x;
    if (i < n) out[i] += bscan[blockIdx.x];
}

// fused post-scan: [0,196) invsqrt | [196,3321) atomic-free fill | [3321,5470) prescale xs
__global__ void k_post_scan(const int* __restrict__ ei, const int* __restrict__ ecsbuf,
                            const int* __restrict__ rank, const int* __restrict__ prefix,
                            const int* __restrict__ deg_out, const float* __restrict__ x,
                            float* __restrict__ inv_out, float* __restrict__ inv_in,
                            int* __restrict__ src_sorted, float* __restrict__ xs) {
    int bx = blockIdx.x;
    if (bx < 196) {
        int n = bx * 256 + threadIdx.x;
        if (n >= N_NODES) return;
        int di = ecsbuf[n + 2] - ecsbuf[n + 1];
        int a = deg_out[n]; if (a < 1) a = 1;
        if (di < 1) di = 1;
        inv_out[n] = 1.0f / sqrtf((float)a);
        inv_in[n]  = 1.0f / sqrtf((float)di);
    } else if (bx < 3321) {
        int e = (bx - 196) * 256 + threadIdx.x;
        if (e < N_EDGES) {
            int d = ei[N_EDGES + e];
            int rc = rank[e];
            int c = rc & 31, r = rc >> 5;
            src_sorted[ecsbuf[1 + d] + prefix[c * NPAD + d] + r] = ei[e];
        }
    } else {
        int idx = (bx - 3321) * 256 + threadIdx.x;   // n*11 + f2
        if (idx >= N_NODES * 11) return;
        int n = idx / 11;
        int f2 = idx - n * 11;
        int a = deg_out[n]; if (a < 1) a = 1;
        float sc = 1.0f / sqrtf((float)a);
        float2 v = *(const float2*)&x[n * 22 + f2 * 2];
        v.x *= sc; v.y *= sc;
        *(float2*)&xs[n * 22 + f2 * 2] = v;
    }
}

// ---------------- aggregation ----------------

// layer 0: gather pre-scaled xs (width 22), *inv_in, -> fp16 A (K pad 32).
__global__ void k_agg22(const float* __restrict__ xs,
                        const int* __restrict__ ecsbuf, const int* __restrict__ srcs,
                        const float* __restrict__ inv_in, _Float16* __restrict__ A) {
    int idx = blockIdx.x * 256 + threadIdx.x;
    int n = idx >> 4, f2 = idx & 15;
    if (n >= N_NODES) return;
    float ax = 0.f, ay = 0.f;
    if (f2 <= 10) {
        const float2* xb = (const float2*)(xs) + f2;
        int e = ecsbuf[n + 1], end = ecsbuf[n + 2];
        for (; e + 3 < end; e += 4) {
            int s0 = srcs[e], s1 = srcs[e + 1], s2 = srcs[e + 2], s3 = srcs[e + 3];
            float2 v0 = xb[s0 * 11], v1 = xb[s1 * 11];
            float2 v2 = xb[s2 * 11], v3 = xb[s3 * 11];
            ax += (v0.x + v1.x) + (v2.x + v3.x);
            ay += (v0.y + v1.y) + (v2.y + v3.y);
        }
        for (; e < end; ++e) {
            float2 v0 = xb[srcs[e] * 11];
            ax += v0.x;
            ay += v0.y;
        }
        float si = inv_in[n];
        ax *= si; ay *= si;
    }
    half2_t h2 = {(_Float16)ax, (_Float16)ay};
    *(half2_t*)&A[n * 32 + f2 * 2] = h2;
}

// width-220 gather (h stored fp16, row = 224 halfs = 448 B = 4 sectors) + *inv_in
// -> fp16 A (single rounding; r12).  One node per 64-lane group; lanes 0..54
// own 4 features (8 B half4 loads); 8 loads in flight; fp32 accumulation.
__global__ __launch_bounds__(256) void k_agg220(const _Float16* __restrict__ h,
                                                const int* __restrict__ ecsbuf,
                                                const int* __restrict__ srcs,
                                                const float* __restrict__ inv_in,
                                                _Float16* __restrict__ A) {
    int lane = threadIdx.x & 63;
    int n = blockIdx.x * 4 + (threadIdx.x >> 6);
    if (n >= N_NODES || lane >= 56) return;   // no barriers; early-exit safe
    size_t ob = (size_t)n * 224 + lane * 4;
    if (lane == 55) {                          // K-pad columns 220..223 = 0
        half4 z = {(_Float16)0.f, (_Float16)0.f, (_Float16)0.f, (_Float16)0.f};
        *(half4*)&A[ob] = z;
        return;
    }
    int f4 = lane * 4;
    const _Float16* hb = h + f4;
    int e = ecsbuf[n + 1], end = ecsbuf[n + 2];
    float4 a0 = {0,0,0,0}, a1 = {0,0,0,0}, a2 = {0,0,0,0}, a3 = {0,0,0,0};
    for (; e + 7 < end; e += 8) {
        int s0 = srcs[e],     s1 = srcs[e + 1], s2 = srcs[e + 2], s3 = srcs[e + 3];
        int s4 = srcs[e + 4], s5 = srcs[e + 5], s6 = srcs[e + 6], s7 = srcs[e + 7];
        half4 v0 = *(const half4*)(hb + (size_t)s0 * HSTR);
        half4 v1 = *(const half4*)(hb + (size_t)s1 * HSTR);
        half4 v2 = *(const half4*)(hb + (size_t)s2 * HSTR);
        half4 v3 = *(const half4*)(hb + (size_t)s3 * HSTR);
        half4 v4 = *(const half4*)(hb + (size_t)s4 * HSTR);
        half4 v5 = *(const half4*)(hb + (size_t)s5 * HSTR);
        half4 v6 = *(const half4*)(hb + (size_t)s6 * HSTR);
        half4 v7 = *(const half4*)(hb + (size_t)s7 * HSTR);
        a0.x += (float)v0.x; a0.y += (float)v0.y; a0.z += (float)v0.z; a0.w += (float)v0.w;
        a1.x += (float)v1.x; a1.y += (float)v1.y; a1.z += (float)v1.z; a1.w += (float)v1.w;
        a2.x += (float)v2.x; a2.y += (float)v2.y; a2.z += (float)v2.z; a2.w += (float)v2.w;
        a3.x += (float)v3.x; a3.y += (float)v3.y; a3.z += (float)v3.z; a3.w += (float)v3.w;
        a0.x += (float)v4.x; a0.y += (float)v4.y; a0.z += (float)v4.z; a0.w += (float)v4.w;
        a1.x += (float)v5.x; a1.y += (float)v5.y; a1.z += (float)v5.z; a1.w += (float)v5.w;
        a2.x += (float)v6.x; a2.y += (float)v6.y; a2.z += (float)v6.z; a2.w += (float)v6.w;
        a3.x += (float)v7.x; a3.y += (float)v7.y; a3.z += (float)v7.z; a3.w += (float)v7.w;
    }
    for (; e + 3 < end; e += 4) {
        int s0 = srcs[e], s1 = srcs[e + 1], s2 = srcs[e + 2], s3 = srcs[e + 3];
        half4 v0 = *(const half4*)(hb + (size_t)s0 * HSTR);
        half4 v1 = *(const half4*)(hb + (size_t)s1 * HSTR);
        half4 v2 = *(const half4*)(hb + (size_t)s2 * HSTR);
        half4 v3 = *(const half4*)(hb + (size_t)s3 * HSTR);
        a0.x += (float)v0.x; a0.y += (float)v0.y; a0.z += (float)v0.z; a0.w += (float)v0.w;
        a1.x += (float)v1.x; a1.y += (float)v1.y; a1.z += (float)v1.z; a1.w += (float)v1.w;
        a2.x += (float)v2.x; a2.y += (float)v2.y; a2.z += (float)v2.z; a2.w += (float)v2.w;
        a3.x += (float)v3.x; a3.y += (float)v3.y; a3.z += (float)v3.z; a3.w += (float)v3.w;
    }
    for (; e < end; ++e) {
        half4 v = *(const half4*)(hb + (size_t)srcs[e] * HSTR);
        a0.x += (float)v.x; a0.y += (float)v.y; a0.z += (float)v.z; a0.w += (float)v.w;
    }
    float sc = inv_in[n];
    half4 o;
    o.x = (_Float16)(((a0.x + a1.x) + (a2.x + a3.x)) * sc);
    o.y = (_Float16)(((a0.y + a1.y) + (a2.y + a3.y)) * sc);
    o.z = (_Float16)(((a0.z + a1.z) + (a2.z + a3.z)) * sc);
    o.w = (_Float16)(((a0.w + a1.w) + (a2.w + a3.w)) * sc);
    *(half4*)&A[ob] = o;
}

// layer 3: gather tmp10 halves (width 10 x 2, 4 MB -> L2-resident), *inv_in + bias
__global__ void k_agg10_epi(const float* __restrict__ tmp, const int* __restrict__ ecsbuf,
                            const int* __restrict__ srcs, const float* __restrict__ inv_in,
                            const float* __restrict__ bias, float* __restrict__ out) {
    int idx = blockIdx.x * 256 + threadIdx.x;
    if (idx >= N_NODES * 5) return;
    int n = idx / 5;
    int f2 = idx - n * 5;
    const float2* tb0 = (const float2*)(tmp) + f2;
    const float2* tb1 = (const float2*)(tmp + (size_t)NPAD * 10) + f2;
    float ax = 0.f, ay = 0.f;
    int e = ecsbuf[n + 1], end = ecsbuf[n + 2];
    for (; e + 1 < end; e += 2) {
        float2 u0 = tb0[srcs[e] * 5],     w0 = tb1[srcs[e] * 5];
        float2 u1 = tb0[srcs[e + 1] * 5], w1 = tb1[srcs[e + 1] * 5];
        ax += (u0.x + w0.x) + (u1.x + w1.x);
        ay += (u0.y + w0.y) + (u1.y + w1.y);
    }
    if (e < end) {
        float2 u0 = tb0[srcs[e] * 5], w0 = tb1[srcs[e] * 5];
        ax += u0.x + w0.x;
        ay += u0.y + w0.y;
    }
    float si = inv_in[n];
    float2 o;
    o.x = ax * si + bias[f2 * 2];
    o.y = ay * si + bias[f2 * 2 + 1];
    *(float2*)&out[n * 10 + f2 * 2] = o;
}

// ---------------- f16 MFMA GEMM: A fp16, W split-fp16 ----------------
// D = A * (W_hi + W_lo): 2 MFMAs + 3 16B loads per (ks,ct) fragment (was 3/4).
// Wave = 16 rows x 112 cols (acc[7] = 28 VGPR, no spill at (256,4)).
// Block = 4 waves = 64 rows x one col-half; grid 1568.
// XCD-aligned row mapping kept from r8/r10 (verified bijective + passing; perf
// null but harmless): row(i) = 4s + 512v + 32*(4w + i/4) + i%4.
template <int KSTEPS, int LDA, bool FUSE_W3>
__global__ __launch_bounds__(256, 4) void k_gemm_mfma(const _Float16* __restrict__ A,
                                                      const _Float16* __restrict__ WT_hi,
                                                      const _Float16* __restrict__ WT_lo,
                                                      const float* __restrict__ bias,
                                                      const float* __restrict__ post,
                                                      _Float16* __restrict__ out,
                                                      const float* __restrict__ W3,
                                                      float* __restrict__ tmp) {
    constexpr bool SWZ = (LDA == 224);
    int tid = threadIdx.x;
    int l = tid & 63, w = tid >> 6;
    int lrow = l & 15, q = l >> 4;
    int bid = blockIdx.x;

    int ch, s = 0, v = 0, rt = 0;
    if constexpr (SWZ) {
        s = bid & 7;
        int u = bid >> 3;
        ch = u & 1;
        v = u >> 1;                 // [0,98)
    } else {
        ch = bid & 1;
        rt = (bid >> 1) * 64 + w * 16;
    }
    int cb = ch * 112;

    // logical tile row i (0..15) -> physical A/out row
    auto prow = [&](int i) -> int {
        if constexpr (SWZ) return 4 * s + 512 * v + 32 * (4 * w + (i >> 2)) + (i & 3);
        else return rt + i;
    };

    int arow = prow(lrow);
    const _Float16* pa  = A + (size_t)arow * LDA + q * 8;
    const _Float16* pbh = WT_hi + (size_t)(cb + lrow) * LDA + q * 8;
    const _Float16* pbl = WT_lo + (size_t)(cb + lrow) * LDA + q * 8;

    f32x4 acc[7];
#pragma unroll
    for (int ct = 0; ct < 7; ++ct) acc[ct] = (f32x4){0.f, 0.f, 0.f, 0.f};

#pragma unroll
    for (int ks = 0; ks < KSTEPS; ++ks) {
        int k0 = ks * 32;
        half8 a = *(const half8*)(const void*)(pa + k0);
#pragma unroll
        for (int ct = 0; ct < 7; ++ct) {
            size_t boff = (size_t)(ct * 16) * LDA + k0;
            half8 bh = *(const half8*)(const void*)(pbh + boff);
            half8 bl = *(const half8*)(const void*)(pbl + boff);
            acc[ct] = mfma16f(a, bh, acc[ct]);
            acc[ct] = mfma16f(a, bl, acc[ct]);
        }
    }

    float pv[4];
#pragma unroll
    for (int r = 0; r < 4; ++r) {
        int r0 = prow(q * 4 + r);
        pv[r] = (r0 < N_NODES) ? post[r0] : 0.f;
    }

    if (!FUSE_W3) {
#pragma unroll
        for (int ct = 0; ct < 7; ++ct) {
            int col = cb + ct * 16 + lrow;
            if (col >= 220) continue;
            float bv = bias[col];
#pragma unroll
            for (int r = 0; r < 4; ++r) {
                int r0 = prow(q * 4 + r);
                if (r0 < N_NODES)
                    out[(size_t)r0 * HSTR + col] = (_Float16)(pv[r] * fast_tanh(acc[ct][r] + bv));
            }
        }
    } else {
        float p[4][10];
#pragma unroll
        for (int r = 0; r < 4; ++r)
#pragma unroll
            for (int j = 0; j < 10; ++j) p[r][j] = 0.f;
#pragma unroll
        for (int ct = 0; ct < 7; ++ct) {
            int col = cb + ct * 16 + lrow;
            bool cok = col < 220;
            float bv = cok ? bias[col] : 0.f;
            float w3v[10];
            if (cok) {
                const float2* wp = (const float2*)&W3[col * 10];
#pragma unroll
                for (int j2 = 0; j2 < 5; ++j2) {
                    float2 t = wp[j2];
                    w3v[2 * j2] = t.x;
                    w3v[2 * j2 + 1] = t.y;
                }
            } else {
#pragma unroll
                for (int j = 0; j < 10; ++j) w3v[j] = 0.f;
            }
#pragma unroll
            for (int r = 0; r < 4; ++r) {
                float h2 = pv[r] * fast_tanh(acc[ct][r] + bv);
#pragma unroll
                for (int j = 0; j < 10; ++j) p[r][j] += h2 * w3v[j];
            }
        }
        // reduce over the 16 lanes (same q) sharing each row
#pragma unroll
        for (int r = 0; r < 4; ++r)
#pragma unroll
            for (int j = 0; j < 10; ++j) {
                float vv = p[r][j];
                vv += __shfl_xor(vv, 1, 64);
                vv += __shfl_xor(vv, 2, 64);
                vv += __shfl_xor(vv, 4, 64);
                vv += __shfl_xor(vv, 8, 64);
                p[r][j] = vv;
            }
        if (lrow == 0) {
#pragma unroll
            for (int r = 0; r < 4; ++r) {
                int row = prow(q * 4 + r);
                if (row < N_NODES) {
                    float* tp = tmp + ((size_t)ch * NPAD + row) * 10;
#pragma unroll
                    for (int j2 = 0; j2 < 5; ++j2) {
                        float2 o = {p[r][2 * j2], p[r][2 * j2 + 1]};
                        *(float2*)&tp[2 * j2] = o;
                    }
                }
            }
        }
    }
}

// ---------------- launch ----------------

extern "C" void kernel_launch(void* const* d_in, const int* in_sizes, int n_in,
                              void* d_out, int out_size, void* d_ws, size_t ws_size,
                              hipStream_t stream) {
    const float* x  = (const float*)d_in[0];
    const float* W0 = (const float*)d_in[1];
    const float* b0 = (const float*)d_in[2];
    const float* W1 = (const float*)d_in[3];
    const float* b1 = (const float*)d_in[4];
    const float* W2 = (const float*)d_in[5];
    const float* b2 = (const float*)d_in[6];
    const float* W3 = (const float*)d_in[7];
    const float* b3 = (const float*)d_in[8];
    const int*   ei = (const int*)d_in[9];
    float* out = (float*)d_out;

    int* ws = (int*)d_ws;
    // word offsets (wt buffers = fp16 splits, same word sizes as before)
    int* ecsbuf     = ws + 0;               // 50432 (50178 used; [0]=0)
    int* deg_out    = ws + 50432;           // 50176
    int* bsumA      = ws + 100608;          // 256 (196 used)
    float* inv_out  = (float*)(ws + 100864);
    float* inv_in   = (float*)(ws + 151040);
    int* src_sorted = ws + 201216;          // 800000
    _Float16* wt0h = (_Float16*)(ws + 1001216);   // 3584 w
    _Float16* wt0l = (_Float16*)(ws + 1004800);   // 3584 w
    _Float16* wt1h = (_Float16*)(ws + 1008384);   // 25088 w
    _Float16* wt1l = (_Float16*)(ws + 1033472);   // 25088 w
    _Float16* wt2h = (_Float16*)(ws + 1058560);   // 25088 w
    _Float16* wt2l = (_Float16*)(ws + 1083648);   // 25088 w
    _Float16* Abuf = (_Float16*)(ws + 1108736);   // NPAD*224 halfs = 5619712 w
    int* scratch   = ws + 6728448;                // old alo slot, 5619712 w
    _Float16* hbuf = (_Float16*)(ws + 12348160);  // 50000*224 halfs = 2800000 w
    float* tmp10 = (float*)(ws + 17948160); // 2*NPAD*10 = 1003520 w -> end 18951680
    // aliases in regions not yet live at CSR-build time:
    int* rank     = (int*)Abuf;                   // Abuf words [0, 800000)
    int* cnt_part = scratch;                      // [0, 1605632)
    int* deg_part = scratch + NCHK * NPAD;        // [1605632, 3211264)
    float* xs = (float*)(ws + 1108736 + 3000000); // Abuf words [3000000,4100000): dead by layer-1 agg

    // CSR build: zero global atomics (LDS hist jobs fully overwrite partials)
    k_build<<<676, 256, 0, stream>>>(ei, deg_part, cnt_part, rank,
                                     W0, W1, W2, wt0h, wt0l, wt1h, wt1l, wt2h, wt2l);
    k_sum32<<<196, 256, 0, stream>>>(cnt_part, deg_part, ecsbuf, deg_out);
    k_scan1<<<196, 256, 0, stream>>>(ecsbuf + 1, ecsbuf + 1, bsumA, NPAD);
    k_scan_mid<<<1, 256, 0, stream>>>(bsumA, 196);
    k_scan3<<<196, 256, 0, stream>>>(ecsbuf + 1, bsumA, NPAD);
    k_post_scan<<<5470, 256, 0, stream>>>(ei, ecsbuf, rank, cnt_part, deg_out, x,
                                          inv_out, inv_in, src_sorted, xs);

    int gemm_grid = (NPAD / 64) * 2;         // 1568 (both mappings)
    int agg_grid  = (N_NODES + 3) / 4;       // 12500

    // ---- layer 0
    k_agg22<<<(N_NODES * 16 + 255) / 256, 256, 0, stream>>>(
        xs, ecsbuf, src_sorted, inv_in, Abuf);
    k_gemm_mfma<1, 32, false><<<gemm_grid, 256, 0, stream>>>(
        Abuf, wt0h, wt0l, b0, inv_out, hbuf, nullptr, nullptr);

    // ---- layer 1
    k_agg220<<<agg_grid, 256, 0, stream>>>(hbuf, ecsbuf, src_sorted, inv_in, Abuf);
    k_gemm_mfma<7, 224, false><<<gemm_grid, 256, 0, stream>>>(
        Abuf, wt1h, wt1l, b1, inv_out, hbuf, nullptr, nullptr);

    // ---- layer 2 (+ fused W3 projection; h2 never materialized)
    k_agg220<<<agg_grid, 256, 0, stream>>>(hbuf, ecsbuf, src_sorted, inv_in, Abuf);
    k_gemm_mfma<7, 224, true><<<gemm_grid, 256, 0, stream>>>(
        Abuf, wt2h, wt2l, b2, inv_out, nullptr, W3, tmp10);

    // ---- layer 3
    k_agg10_epi<<<(N_NODES * 5 + 255) / 256, 256, 0, stream>>>(
        tmp10, ecsbuf, src_sorted, inv_in, b3, out);
}

// Round 13
// 411.435 us; speedup vs baseline: 1.5342x; 1.0262x over previous
//
#include <hip/hip_runtime.h>
#include <math.h>

#define N_NODES 50000
#define N_EDGES 800000
#define NPAD 50176
#define HSTR 224   // hbuf row stride in HALFS: 448 B = exactly 4 x 128B sectors per row fetch
#define RBIN 12544 // bins per histogram range (NPAD/4), 49 KB LDS as int
#define NCHK 32    // edge chunks; chunk = 25000 edges
// ecsbuf (NPAD+2 ints): after k_sum32, ecsbuf[1+d] = total in-degree count;
// after scans, ecsbuf[1+d] = start(d). Readers: start(n)=ecsbuf[n+1], end=ecsbuf[n+2].
// CSR build: ZERO global atomics (r7: atomic stream ~22G/s coherence-bound;
// r11: 4 ranges x 32 chunks LDS hist = win, k_build ~25us).
// GEMM numerics (r12): A in SINGLE fp16, W in split-fp16 hi+lo,
// f16 MFMA: D = A*(Whi) + A*(Wlo). absmax stayed 1.5e-5.
// GEMM schedule (r13): compiler register-starved the unrolled loop (VGPR=40 ->
// ~3 loads in flight, ~870 cy/load serialization). Fix: per-ks explicit
// B-fragment register array (14 half8, statically indexed) loaded BEFORE the
// MFMA cluster -> ~15 loads in flight, ~105 VGPR, still 4 waves/SIMD.

typedef __attribute__((ext_vector_type(8))) _Float16 half8;
typedef __attribute__((ext_vector_type(4))) float f32x4;
typedef __attribute__((ext_vector_type(4))) _Float16 half4;
typedef __attribute__((ext_vector_type(2))) _Float16 half2_t;

// ---------------- helpers ----------------

__device__ __forceinline__ float fast_tanh(float x) {
    float e = __expf(2.0f * x);
    float r = __builtin_amdgcn_rcpf(e + 1.0f);
    return 1.0f - 2.0f * r;
}

__device__ __forceinline__ f32x4 mfma16f(half8 a, half8 b, f32x4 c) {
    return __builtin_amdgcn_mfma_f32_16x16x32_f16(a, b, c, 0, 0, 0);
}

// split W to fp16 hi + fp16 lo (hi = RNE(v); lo = RNE(v - hi))
__device__ __forceinline__ void wsplit_one(const float* __restrict__ W, int KIN, int LDA,
                                           _Float16* __restrict__ WT_hi,
                                           _Float16* __restrict__ WT_lo, int idx) {
    int n = idx / LDA;
    int k = idx - n * LDA;
    float v = (n < 220 && k < KIN) ? W[k * 220 + n] : 0.f;
    _Float16 hi = (_Float16)v;
    _Float16 lo = (_Float16)(v - (float)hi);
    WT_hi[idx] = hi;
    WT_lo[idx] = lo;
}

// ---------------- CSR build (zero global atomics) ----------------

// partitioned launch:
// [0,128)    dst rank job: rng = bx>>5, chk = bx&31 (4 ranges x 32 chunks)
// [128,256)  src hist job: same decomposition
// [256,284)  wsplit W0 | [284,480) W1 | [480,676) W2
__global__ void k_build(const int* __restrict__ ei, int* __restrict__ deg_part,
                        int* __restrict__ cnt_part, int* __restrict__ rank,
                        const float* __restrict__ W0, const float* __restrict__ W1,
                        const float* __restrict__ W2,
                        _Float16* __restrict__ wt0h, _Float16* __restrict__ wt0l,
                        _Float16* __restrict__ wt1h, _Float16* __restrict__ wt1l,
                        _Float16* __restrict__ wt2h, _Float16* __restrict__ wt2l) {
    __shared__ int hb[RBIN];   // 49 KB -> 3 blocks/CU
    int bx = blockIdx.x;
    if (bx < 128) {
        int rng = bx >> 5, chk = bx & 31;
        int lo = rng * RBIN;
        for (int i = threadIdx.x; i < RBIN; i += 256) hb[i] = 0;
        __syncthreads();
        int ebeg = chk * 25000, eend = ebeg + 25000;
        for (int e = ebeg + threadIdx.x; e < eend; e += 256) {
            int d = ei[N_EDGES + e];
            unsigned idx = (unsigned)(d - lo);
            if (idx < (unsigned)RBIN) {
                int lr = atomicAdd(&hb[idx], 1);     // LDS returning add
                rank[e] = (lr << 5) | chk;
            }
        }
        __syncthreads();
        for (int i = threadIdx.x; i < RBIN; i += 256)
            cnt_part[chk * NPAD + lo + i] = hb[i];
    } else if (bx < 256) {
        int b2 = bx - 128;
        int rng = b2 >> 5, chk = b2 & 31;
        int lo = rng * RBIN;
        for (int i = threadIdx.x; i < RBIN; i += 256) hb[i] = 0;
        __syncthreads();
        int ebeg = chk * 25000, eend = ebeg + 25000;
        for (int e = ebeg + threadIdx.x; e < eend; e += 256) {
            int s = ei[e];
            unsigned idx = (unsigned)(s - lo);
            if (idx < (unsigned)RBIN) atomicAdd(&hb[idx], 1);
        }
        __syncthreads();
        for (int i = threadIdx.x; i < RBIN; i += 256)
            deg_part[chk * NPAD + lo + i] = hb[i];
    } else if (bx < 284) {
        int idx = (bx - 256) * 256 + threadIdx.x;           // 224*32 = 7168
        if (idx < 224 * 32) wsplit_one(W0, 22, 32, wt0h, wt0l, idx);
    } else if (bx < 480) {
        int idx = (bx - 284) * 256 + threadIdx.x;           // 224*224 = 50176
        wsplit_one(W1, 220, 224, wt1h, wt1l, idx);
    } else {
        int idx = (bx - 480) * 256 + threadIdx.x;
        wsplit_one(W2, 220, 224, wt2h, wt2l, idx);
    }
}

// fold 32 chunk-partials: cnt_part -> in-place exclusive per-bin prefix,
// ecsbuf[1+d] = total in-degree, deg_out[d] = total out-degree.
__global__ void k_sum32(int* __restrict__ cnt_part, const int* __restrict__ deg_part,
                        int* __restrict__ ecsbuf, int* __restrict__ deg_out) {
    int d = blockIdx.x * 256 + threadIdx.x;
    if (d >= NPAD) return;
    int s = 0;
#pragma unroll
    for (int c = 0; c < NCHK; ++c) {
        int v = cnt_part[c * NPAD + d];
        cnt_part[c * NPAD + d] = s;
        s += v;
    }
    ecsbuf[1 + d] = s;
    if (d == 0) ecsbuf[0] = 0;
    int t = 0;
#pragma unroll
    for (int c = 0; c < NCHK; ++c) t += deg_part[c * NPAD + d];
    deg_out[d] = t;
}

__global__ void k_scan1(const int* __restrict__ in, int* __restrict__ out,
                        int* __restrict__ bsum, int n) {
    __shared__ int s[256];
    int i = blockIdx.x * 256 + threadIdx.x;
    int v = (i < n) ? in[i] : 0;
    s[threadIdx.x] = v;
    __syncthreads();
    for (int off = 1; off < 256; off <<= 1) {
        int t = (threadIdx.x >= off) ? s[threadIdx.x - off] : 0;
        __syncthreads();
        s[threadIdx.x] += t;
        __syncthreads();
    }
    if (i < n) out[i] = s[threadIdx.x] - v;   // exclusive
    if (threadIdx.x == 255 && bsum) bsum[blockIdx.x] = s[255];
}

__global__ void k_scan_mid(int* __restrict__ a, int n) {
    __shared__ int s[256];
    __shared__ int carry;
    if (threadIdx.x == 0) carry = 0;
    for (int base = 0; base < n; base += 256) {
        int i = base + threadIdx.x;
        int v = (i < n) ? a[i] : 0;
        s[threadIdx.x] = v;
        __syncthreads();
        for (int off = 1; off < 256; off <<= 1) {
            int t = (threadIdx.x >= off) ? s[threadIdx.x - off] : 0;
            __syncthreads();
            s[threadIdx.x] += t;
            __syncthreads();
        }
        int c = carry;
        if (i < n) a[i] = s[threadIdx.x] - v + c;
        __syncthreads();
        if (threadIdx.x == 0) carry = c + s[255];
        __syncthreads();
    }
}

__global__ void k_scan3(int* __restrict__ out, const int* __restrict__ bscan, int n) {
    int i = blockIdx.x * 256 + threadIdx.x;
    if (i < n) out[i] += bscan[blockIdx.x];
}

// fused post-scan: [0,196) invsqrt | [196,3321) atomic-free fill | [3321,5470) prescale xs
__global__ void k_post_scan(const int* __restrict__ ei, const int* __restrict__ ecsbuf,
                            const int* __restrict__ rank, const int* __restrict__ prefix,
                            const int* __restrict__ deg_out, const float* __restrict__ x,
                            float* __restrict__ inv_out, float* __restrict__ inv_in,
                            int* __restrict__ src_sorted, float* __restrict__ xs) {
    int bx = blockIdx.x;
    if (bx < 196) {
        int n = bx * 256 + threadIdx.x;
        if (n >= N_NODES) return;
        int di = ecsbuf[n + 2] - ecsbuf[n + 1];
        int a = deg_out[n]; if (a < 1) a = 1;
        if (di < 1) di = 1;
        inv_out[n] = 1.0f / sqrtf((float)a);
        inv_in[n]  = 1.0f / sqrtf((float)di);
    } else if (bx < 3321) {
        int e = (bx - 196) * 256 + threadIdx.x;
        if (e < N_EDGES) {
            int d = ei[N_EDGES + e];
            int rc = rank[e];
            int c = rc & 31, r = rc >> 5;
            src_sorted[ecsbuf[1 + d] + prefix[c * NPAD + d] + r] = ei[e];
        }
    } else {
        int idx = (bx - 3321) * 256 + threadIdx.x;   // n*11 + f2
        if (idx >= N_NODES * 11) return;
        int n = idx / 11;
        int f2 = idx - n * 11;
        int a = deg_out[n]; if (a < 1) a = 1;
        float sc = 1.0f / sqrtf((float)a);
        float2 v = *(const float2*)&x[n * 22 + f2 * 2];
        v.x *= sc; v.y *= sc;
        *(float2*)&xs[n * 22 + f2 * 2] = v;
    }
}

// ---------------- aggregation ----------------

// layer 0: gather pre-scaled xs (width 22), *inv_in, -> fp16 A (K pad 32).
__global__ void k_agg22(const float* __restrict__ xs,
                        const int* __restrict__ ecsbuf, const int* __restrict__ srcs,
                        const float* __restrict__ inv_in, _Float16* __restrict__ A) {
    int idx = blockIdx.x * 256 + threadIdx.x;
    int n = idx >> 4, f2 = idx & 15;
    if (n >= N_NODES) return;
    float ax = 0.f, ay = 0.f;
    if (f2 <= 10) {
        const float2* xb = (const float2*)(xs) + f2;
        int e = ecsbuf[n + 1], end = ecsbuf[n + 2];
        for (; e + 3 < end; e += 4) {
            int s0 = srcs[e], s1 = srcs[e + 1], s2 = srcs[e + 2], s3 = srcs[e + 3];
            float2 v0 = xb[s0 * 11], v1 = xb[s1 * 11];
            float2 v2 = xb[s2 * 11], v3 = xb[s3 * 11];
            ax += (v0.x + v1.x) + (v2.x + v3.x);
            ay += (v0.y + v1.y) + (v2.y + v3.y);
        }
        for (; e < end; ++e) {
            float2 v0 = xb[srcs[e] * 11];
            ax += v0.x;
            ay += v0.y;
        }
        float si = inv_in[n];
        ax *= si; ay *= si;
    }
    half2_t h2 = {(_Float16)ax, (_Float16)ay};
    *(half2_t*)&A[n * 32 + f2 * 2] = h2;
}

// width-220 gather (h stored fp16, row = 224 halfs = 448 B = 4 sectors) + *inv_in
// -> fp16 A (single rounding).  One node per 64-lane group; lanes 0..54 own 4
// features (8 B half4 loads); 8 loads in flight; fp32 accumulation.
__global__ __launch_bounds__(256) void k_agg220(const _Float16* __restrict__ h,
                                                const int* __restrict__ ecsbuf,
                                                const int* __restrict__ srcs,
                                                const float* __restrict__ inv_in,
                                                _Float16* __restrict__ A) {
    int lane = threadIdx.x & 63;
    int n = blockIdx.x * 4 + (threadIdx.x >> 6);
    if (n >= N_NODES || lane >= 56) return;   // no barriers; early-exit safe
    size_t ob = (size_t)n * 224 + lane * 4;
    if (lane == 55) {                          // K-pad columns 220..223 = 0
        half4 z = {(_Float16)0.f, (_Float16)0.f, (_Float16)0.f, (_Float16)0.f};
        *(half4*)&A[ob] = z;
        return;
    }
    int f4 = lane * 4;
    const _Float16* hb = h + f4;
    int e = ecsbuf[n + 1], end = ecsbuf[n + 2];
    float4 a0 = {0,0,0,0}, a1 = {0,0,0,0}, a2 = {0,0,0,0}, a3 = {0,0,0,0};
    for (; e + 7 < end; e += 8) {
        int s0 = srcs[e],     s1 = srcs[e + 1], s2 = srcs[e + 2], s3 = srcs[e + 3];
        int s4 = srcs[e + 4], s5 = srcs[e + 5], s6 = srcs[e + 6], s7 = srcs[e + 7];
        half4 v0 = *(const half4*)(hb + (size_t)s0 * HSTR);
        half4 v1 = *(const half4*)(hb + (size_t)s1 * HSTR);
        half4 v2 = *(const half4*)(hb + (size_t)s2 * HSTR);
        half4 v3 = *(const half4*)(hb + (size_t)s3 * HSTR);
        half4 v4 = *(const half4*)(hb + (size_t)s4 * HSTR);
        half4 v5 = *(const half4*)(hb + (size_t)s5 * HSTR);
        half4 v6 = *(const half4*)(hb + (size_t)s6 * HSTR);
        half4 v7 = *(const half4*)(hb + (size_t)s7 * HSTR);
        a0.x += (float)v0.x; a0.y += (float)v0.y; a0.z += (float)v0.z; a0.w += (float)v0.w;
        a1.x += (float)v1.x; a1.y += (float)v1.y; a1.z += (float)v1.z; a1.w += (float)v1.w;
        a2.x += (float)v2.x; a2.y += (float)v2.y; a2.z += (float)v2.z; a2.w += (float)v2.w;
        a3.x += (float)v3.x; a3.y += (float)v3.y; a3.z += (float)v3.z; a3.w += (float)v3.w;
        a0.x += (float)v4.x; a0.y += (float)v4.y; a0.z += (float)v4.z; a0.w += (float)v4.w;
        a1.x += (float)v5.x; a1.y += (float)v5.y; a1.z += (float)v5.z; a1.w += (float)v5.w;
        a2.x += (float)v6.x; a2.y += (float)v6.y; a2.z += (float)v6.z; a2.w += (float)v6.w;
        a3.x += (float)v7.x; a3.y += (float)v7.y; a3.z += (float)v7.z; a3.w += (float)v7.w;
    }
    for (; e + 3 < end; e += 4) {
        int s0 = srcs[e], s1 = srcs[e + 1], s2 = srcs[e + 2], s3 = srcs[e + 3];
        half4 v0 = *(const half4*)(hb + (size_t)s0 * HSTR);
        half4 v1 = *(const half4*)(hb + (size_t)s1 * HSTR);
        half4 v2 = *(const half4*)(hb + (size_t)s2 * HSTR);
        half4 v3 = *(const half4*)(hb + (size_t)s3 * HSTR);
        a0.x += (float)v0.x; a0.y += (float)v0.y; a0.z += (float)v0.z; a0.w += (float)v0.w;
        a1.x += (float)v1.x; a1.y += (float)v1.y; a1.z += (float)v1.z; a1.w += (float)v1.w;
        a2.x += (float)v2.x; a2.y += (float)v2.y; a2.z += (float)v2.z; a2.w += (float)v2.w;
        a3.x += (float)v3.x; a3.y += (float)v3.y; a3.z += (float)v3.z; a3.w += (float)v3.w;
    }
    for (; e < end; ++e) {
        half4 v = *(const half4*)(hb + (size_t)srcs[e] * HSTR);
        a0.x += (float)v.x; a0.y += (float)v.y; a0.z += (float)v.z; a0.w += (float)v.w;
    }
    float sc = inv_in[n];
    half4 o;
    o.x = (_Float16)(((a0.x + a1.x) + (a2.x + a3.x)) * sc);
    o.y = (_Float16)(((a0.y + a1.y) + (a2.y + a3.y)) * sc);
    o.z = (_Float16)(((a0.z + a1.z) + (a2.z + a3.z)) * sc);
    o.w = (_Float16)(((a0.w + a1.w) + (a2.w + a3.w)) * sc);
    *(half4*)&A[ob] = o;
}

// layer 3: gather tmp10 halves (width 10 x 2, 4 MB -> L2-resident), *inv_in + bias
__global__ void k_agg10_epi(const float* __restrict__ tmp, const int* __restrict__ ecsbuf,
                            const int* __restrict__ srcs, const float* __restrict__ inv_in,
                            const float* __restrict__ bias, float* __restrict__ out) {
    int idx = blockIdx.x * 256 + threadIdx.x;
    if (idx >= N_NODES * 5) return;
    int n = idx / 5;
    int f2 = idx - n * 5;
    const float2* tb0 = (const float2*)(tmp) + f2;
    const float2* tb1 = (const float2*)(tmp + (size_t)NPAD * 10) + f2;
    float ax = 0.f, ay = 0.f;
    int e = ecsbuf[n + 1], end = ecsbuf[n + 2];
    for (; e + 1 < end; e += 2) {
        float2 u0 = tb0[srcs[e] * 5],     w0 = tb1[srcs[e] * 5];
        float2 u1 = tb0[srcs[e + 1] * 5], w1 = tb1[srcs[e + 1] * 5];
        ax += (u0.x + w0.x) + (u1.x + w1.x);
        ay += (u0.y + w0.y) + (u1.y + w1.y);
    }
    if (e < end) {
        float2 u0 = tb0[srcs[e] * 5], w0 = tb1[srcs[e] * 5];
        ax += u0.x + w0.x;
        ay += u0.y + w0.y;
    }
    float si = inv_in[n];
    float2 o;
    o.x = ax * si + bias[f2 * 2];
    o.y = ay * si + bias[f2 * 2 + 1];
    *(float2*)&out[n * 10 + f2 * 2] = o;
}

// ---------------- f16 MFMA GEMM: A fp16, W split-fp16, batched loads --------
// Per ks: A + all 14 B fragments loaded into a statically-indexed register
// array BEFORE the MFMA cluster (r13 fix for VGPR=40 load-serialization).
// Wave = 16 rows x 112 cols; block = 4 waves; grid 1568; (256,4) cap 128 VGPR.
// XCD-aligned row mapping kept (verified bijective + passing).
template <int KSTEPS, int LDA, bool FUSE_W3>
__global__ __launch_bounds__(256, 4) void k_gemm_mfma(const _Float16* __restrict__ A,
                                                      const _Float16* __restrict__ WT_hi,
                                                      const _Float16* __restrict__ WT_lo,
                                                      const float* __restrict__ bias,
                                                      const float* __restrict__ post,
                                                      _Float16* __restrict__ out,
                                                      const float* __restrict__ W3,
                                                      float* __restrict__ tmp) {
    constexpr bool SWZ = (LDA == 224);
    int tid = threadIdx.x;
    int l = tid & 63, w = tid >> 6;
    int lrow = l & 15, q = l >> 4;
    int bid = blockIdx.x;

    int ch, s = 0, v = 0, rt = 0;
    if constexpr (SWZ) {
        s = bid & 7;
        int u = bid >> 3;
        ch = u & 1;
        v = u >> 1;                 // [0,98)
    } else {
        ch = bid & 1;
        rt = (bid >> 1) * 64 + w * 16;
    }
    int cb = ch * 112;

    // logical tile row i (0..15) -> physical A/out row
    auto prow = [&](int i) -> int {
        if constexpr (SWZ) return 4 * s + 512 * v + 32 * (4 * w + (i >> 2)) + (i & 3);
        else return rt + i;
    };

    int arow = prow(lrow);
    const _Float16* pa  = A + (size_t)arow * LDA + q * 8;
    const _Float16* pbh = WT_hi + (size_t)(cb + lrow) * LDA + q * 8;
    const _Float16* pbl = WT_lo + (size_t)(cb + lrow) * LDA + q * 8;

    f32x4 acc[7];
#pragma unroll
    for (int ct = 0; ct < 7; ++ct) acc[ct] = (f32x4){0.f, 0.f, 0.f, 0.f};

#pragma unroll
    for (int ks = 0; ks < KSTEPS; ++ks) {
        int k0 = ks * 32;
        // issue all 15 loads of this ks before any MFMA (static indices -> regs)
        half8 a = *(const half8*)(const void*)(pa + k0);
        half8 bh[7], bl[7];
#pragma unroll
        for (int ct = 0; ct < 7; ++ct) {
            size_t boff = (size_t)(ct * 16) * LDA + k0;
            bh[ct] = *(const half8*)(const void*)(pbh + boff);
            bl[ct] = *(const half8*)(const void*)(pbl + boff);
        }
#pragma unroll
        for (int ct = 0; ct < 7; ++ct) {
            acc[ct] = mfma16f(a, bh[ct], acc[ct]);
            acc[ct] = mfma16f(a, bl[ct], acc[ct]);
        }
    }

    float pv[4];
#pragma unroll
    for (int r = 0; r < 4; ++r) {
        int r0 = prow(q * 4 + r);
        pv[r] = (r0 < N_NODES) ? post[r0] : 0.f;
    }

    if (!FUSE_W3) {
#pragma unroll
        for (int ct = 0; ct < 7; ++ct) {
            int col = cb + ct * 16 + lrow;
            if (col >= 220) continue;
            float bv = bias[col];
#pragma unroll
            for (int r = 0; r < 4; ++r) {
                int r0 = prow(q * 4 + r);
                if (r0 < N_NODES)
                    out[(size_t)r0 * HSTR + col] = (_Float16)(pv[r] * fast_tanh(acc[ct][r] + bv));
            }
        }
    } else {
        float p[4][10];
#pragma unroll
        for (int r = 0; r < 4; ++r)
#pragma unroll
            for (int j = 0; j < 10; ++j) p[r][j] = 0.f;
#pragma unroll
        for (int ct = 0; ct < 7; ++ct) {
            int col = cb + ct * 16 + lrow;
            bool cok = col < 220;
            float bv = cok ? bias[col] : 0.f;
            float w3v[10];
            if (cok) {
                const float2* wp = (const float2*)&W3[col * 10];
#pragma unroll
                for (int j2 = 0; j2 < 5; ++j2) {
                    float2 t = wp[j2];
                    w3v[2 * j2] = t.x;
                    w3v[2 * j2 + 1] = t.y;
                }
            } else {
#pragma unroll
                for (int j = 0; j < 10; ++j) w3v[j] = 0.f;
            }
#pragma unroll
            for (int r = 0; r < 4; ++r) {
                float h2 = pv[r] * fast_tanh(acc[ct][r] + bv);
#pragma unroll
                for (int j = 0; j < 10; ++j) p[r][j] += h2 * w3v[j];
            }
        }
        // reduce over the 16 lanes (same q) sharing each row
#pragma unroll
        for (int r = 0; r < 4; ++r)
#pragma unroll
            for (int j = 0; j < 10; ++j) {
                float vv = p[r][j];
                vv += __shfl_xor(vv, 1, 64);
                vv += __shfl_xor(vv, 2, 64);
                vv += __shfl_xor(vv, 4, 64);
                vv += __shfl_xor(vv, 8, 64);
                p[r][j] = vv;
            }
        if (lrow == 0) {
#pragma unroll
            for (int r = 0; r < 4; ++r) {
                int row = prow(q * 4 + r);
                if (row < N_NODES) {
                    float* tp = tmp + ((size_t)ch * NPAD + row) * 10;
#pragma unroll
                    for (int j2 = 0; j2 < 5; ++j2) {
                        float2 o = {p[r][2 * j2], p[r][2 * j2 + 1]};
                        *(float2*)&tp[2 * j2] = o;
                    }
                }
            }
        }
    }
}

// ---------------- launch ----------------

extern "C" void kernel_launch(void* const* d_in, const int* in_sizes, int n_in,
                              void* d_out, int out_size, void* d_ws, size_t ws_size,
                              hipStream_t stream) {
    const float* x  = (const float*)d_in[0];
    const float* W0 = (const float*)d_in[1];
    const float* b0 = (const float*)d_in[2];
    const float* W1 = (const float*)d_in[3];
    const float* b1 = (const float*)d_in[4];
    const float* W2 = (const float*)d_in[5];
    const float* b2 = (const float*)d_in[6];
    const float* W3 = (const float*)d_in[7];
    const float* b3 = (const float*)d_in[8];
    const int*   ei = (const int*)d_in[9];
    float* out = (float*)d_out;

    int* ws = (int*)d_ws;
    // word offsets (wt buffers = fp16 splits)
    int* ecsbuf     = ws + 0;               // 50432 (50178 used; [0]=0)
    int* deg_out    = ws + 50432;           // 50176
    int* bsumA      = ws + 100608;          // 256 (196 used)
    float* inv_out  = (float*)(ws + 100864);
    float* inv_in   = (float*)(ws + 151040);
    int* src_sorted = ws + 201216;          // 800000
    _Float16* wt0h = (_Float16*)(ws + 1001216);   // 3584 w
    _Float16* wt0l = (_Float16*)(ws + 1004800);   // 3584 w
    _Float16* wt1h = (_Float16*)(ws + 1008384);   // 25088 w
    _Float16* wt1l = (_Float16*)(ws + 1033472);   // 25088 w
    _Float16* wt2h = (_Float16*)(ws + 1058560);   // 25088 w
    _Float16* wt2l = (_Float16*)(ws + 1083648);   // 25088 w
    _Float16* Abuf = (_Float16*)(ws + 1108736);   // NPAD*224 halfs = 5619712 w
    int* scratch   = ws + 6728448;                // 5619712 w
    _Float16* hbuf = (_Float16*)(ws + 12348160);  // 50000*224 halfs = 2800000 w
    float* tmp10 = (float*)(ws + 17948160); // 2*NPAD*10 = 1003520 w -> end 18951680
    // aliases in regions not yet live at CSR-build time:
    int* rank     = (int*)Abuf;                   // Abuf words [0, 800000)
    int* cnt_part = scratch;                      // [0, 1605632)
    int* deg_part = scratch + NCHK * NPAD;        // [1605632, 3211264)
    float* xs = (float*)(ws + 1108736 + 3000000); // Abuf words [3000000,4100000): dead by layer-1 agg

    // CSR build: zero global atomics (LDS hist jobs fully overwrite partials)
    k_build<<<676, 256, 0, stream>>>(ei, deg_part, cnt_part, rank,
                                     W0, W1, W2, wt0h, wt0l, wt1h, wt1l, wt2h, wt2l);
    k_sum32<<<196, 256, 0, stream>>>(cnt_part, deg_part, ecsbuf, deg_out);
    k_scan1<<<196, 256, 0, stream>>>(ecsbuf + 1, ecsbuf + 1, bsumA, NPAD);
    k_scan_mid<<<1, 256, 0, stream>>>(bsumA, 196);
    k_scan3<<<196, 256, 0, stream>>>(ecsbuf + 1, bsumA, NPAD);
    k_post_scan<<<5470, 256, 0, stream>>>(ei, ecsbuf, rank, cnt_part, deg_out, x,
                                          inv_out, inv_in, src_sorted, xs);

    int gemm_grid = (NPAD / 64) * 2;         // 1568 (both mappings)
    int agg_grid  = (N_NODES + 3) / 4;       // 12500

    // ---- layer 0
    k_agg22<<<(N_NODES * 16 + 255) / 256, 256, 0, stream>>>(
        xs, ecsbuf, src_sorted, inv_in, Abuf);
    k_gemm_mfma<1, 32, false><<<gemm_grid, 256, 0, stream>>>(
        Abuf, wt0h, wt0l, b0, inv_out, hbuf, nullptr, nullptr);

    // ---- layer 1
    k_agg220<<<agg_grid, 256, 0, stream>>>(hbuf, ecsbuf, src_sorted, inv_in, Abuf);
    k_gemm_mfma<7, 224, false><<<gemm_grid, 256, 0, stream>>>(
        Abuf, wt1h, wt1l, b1, inv_out, hbuf, nullptr, nullptr);

    // ---- layer 2 (+ fused W3 projection; h2 never materialized)
    k_agg220<<<agg_grid, 256, 0, stream>>>(hbuf, ecsbuf, src_sorted, inv_in, Abuf);
    k_gemm_mfma<7, 224, true><<<gemm_grid, 256, 0, stream>>>(
        Abuf, wt2h, wt2l, b2, inv_out, nullptr, W3, tmp10);

    // ---- layer 3
    k_agg10_epi<<<(N_NODES * 5 + 255) / 256, 256, 0, stream>>>(
        tmp10, ecsbuf, src_sorted, inv_in, b3, out);
}